// Round 13
// baseline (1583.072 us; speedup 1.0000x reference)
//
#include <hip/hip_runtime.h>

typedef __bf16 bf16;
typedef __bf16 bf16x4 __attribute__((ext_vector_type(4)));
typedef __bf16 bf16x8 __attribute__((ext_vector_type(8)));
typedef float  f32x4  __attribute__((ext_vector_type(4)));

#define DM   1024
#define NH   16
#define DKH  64
#define DFF  4096
#define SEQL 2048
#define NTOK 8192

typedef __attribute__((address_space(1))) void GAS;
typedef __attribute__((address_space(3))) void LAS;

__device__ inline void gload_lds16(const void* g, void* l) {
    __builtin_amdgcn_global_load_lds((GAS*)g, (LAS*)l, 16, 0, 0);
}

// bare v_exp_f32 (exp2) — avoids libm exp2f's range-check sequence
__device__ inline float fast_exp2(float x) {
    float r;
    asm("v_exp_f32 %0, %1" : "=v"(r) : "v"(x));
    return r;
}

// ---------------- cast f32 -> bf16 ----------------
__global__ void cast_f32_bf16(const float* __restrict__ in, bf16* __restrict__ out, long n) {
    long i = ((long)blockIdx.x * 256 + threadIdx.x) * 4;
    long stride = (long)gridDim.x * 256 * 4;
    for (; i < n; i += stride) {
        float4 v = *(const float4*)(in + i);
        bf16x4 o = {(bf16)v.x, (bf16)v.y, (bf16)v.z, (bf16)v.w};
        *(bf16x4*)(out + i) = o;
    }
}

// ---------------- transpose + cast: src[R][C] f32 -> dst[C][R] bf16 ----------------
__global__ void transpose_cast(const float* __restrict__ src, bf16* __restrict__ dst, int R, int C) {
    __shared__ float t[32][33];
    int c0 = blockIdx.x * 32, r0 = blockIdx.y * 32;
    int tx = threadIdx.x, ty = threadIdx.y; // block (32,8)
#pragma unroll
    for (int i = 0; i < 4; ++i)
        t[ty + i * 8][tx] = src[(long)(r0 + ty + i * 8) * C + c0 + tx];
    __syncthreads();
#pragma unroll
    for (int i = 0; i < 4; ++i)
        dst[(long)(c0 + ty + i * 8) * R + r0 + tx] = (bf16)t[tx][ty + i * 8];
}

// ---------------- concat 3 bias vectors (1024 each) ----------------
__global__ void concat3(const float* __restrict__ a, const float* __restrict__ b,
                        const float* __restrict__ c, float* __restrict__ out) {
    int i = blockIdx.x * 256 + threadIdx.x;
    if (i < 1024) out[i] = a[i];
    else if (i < 2048) out[i] = b[i - 1024];
    else if (i < 3072) out[i] = c[i - 2048];
}

// ---------------- build V^T: vt[(b*16+h)*64 + d][s] ----------------
__global__ void build_vt(const bf16* __restrict__ qkv, bf16* __restrict__ vt) {
    __shared__ bf16 t[32][33];
    int bh = blockIdx.z, b = bh >> 4, h = bh & 15;
    int s0 = blockIdx.x * 32, d0 = blockIdx.y * 32;
    int tx = threadIdx.x, ty = threadIdx.y;
#pragma unroll
    for (int i = 0; i < 4; ++i)
        t[ty + i * 8][tx] = qkv[(long)(b * SEQL + s0 + ty + i * 8) * 3072 + 2 * DM + h * DKH + d0 + tx];
    __syncthreads();
#pragma unroll
    for (int i = 0; i < 4; ++i)
        vt[((long)bh * DKH + d0 + ty + i * 8) * SEQL + s0 + tx] = (bf16)t[tx][ty + i * 8];
}

// ---------------- GEMM: r6 schedule, 2-buffer/64KB LDS -> 2 blocks/CU ----------------
// 256xBN tile, 8 waves (2Mx4N, wave=128x(BN/4)), BK=32 K-tiles, 2 LDS buffers
// (64KB: fits TWO co-resident blocks per CU -> cross-block overlap covers the
// vmcnt/barrier drains that pinned MfmaUtil at ~21% with 1 block/CU).
// Full next tile (A+B, 4 loads/thread) staged at iteration top; counted
// vmcnt(4) keeps it in flight while guaranteeing the current tile landed.
// BN=192: j=1 B-stage duplicates cells 512..767 on threads 256..511 (benign
// same-value LDS writes) so every thread issues exactly 4 loads/tile.
// Split-K via blockIdx.z; bias applied only by z==0 (partials summed in add_ln).
template<int BN>
__global__ __launch_bounds__(512, 4)
void gemm8p(const bf16* __restrict__ A, const bf16* __restrict__ Bt,
            const float* __restrict__ bias,
            float* __restrict__ Cf, bf16* __restrict__ Ch,
            int N, int lda, int Klen, int relu, long strideCf) {
    constexpr int NR = BN / 64;            // 256->4, 192->3
    constexpr int WCOL = BN / 4;           // per-wave N extent
    __shared__ bf16 As[2][4][256][8];
    __shared__ bf16 Bs[2][4][BN][8];
    const int tid = threadIdx.x;
    const int lane = tid & 63;
    const int wv = tid >> 6;
    const int wr = wv >> 2, wc = wv & 3;      // 2 x 4 wave grid
    const int lr = lane & 15, lg = lane >> 4;

    unsigned gx = gridDim.x, gy = gridDim.y;
    unsigned nwg = gx * gy * gridDim.z;
    unsigned wg = (blockIdx.z * gy + blockIdx.y) * gx + blockIdx.x;
    unsigned swz = (wg & 7) * (nwg >> 3) + (wg >> 3);
    unsigned bxi = swz % gx;
    unsigned rem2 = swz / gx;
    unsigned byi = rem2 % gy, bzi = rem2 / gy;

    const long brow = (long)byi * 256;
    const long bcol = (long)bxi * BN;
    const bf16* Ap = A + (long)bzi * Klen;
    const bf16* Bp = Bt + (long)bzi * Klen;
    float* Cfp = Cf ? Cf + (long)bzi * strideCf : nullptr;
    const float* biasp = (bzi == 0) ? bias : nullptr;

    auto stageA = [&](int X) {
        const int kt = X * 32, buf = X & 1;
#pragma unroll
        for (int j = 0; j < 2; ++j) {
            int l = j * 512 + tid;
            int kg = l >> 8, row = l & 255;
            gload_lds16(Ap + (brow + row) * (long)lda + kt + kg * 8, &As[buf][kg][row][0]);
        }
    };
    auto stageB = [&](int X) {
        const int kt = X * 32, buf = X & 1;
        {
            int l = tid;                       // cells 0..511
            int kg = l / BN, row = l % BN;
            gload_lds16(Bp + (bcol + row) * (long)lda + kt + kg * 8, &Bs[buf][kg][row][0]);
        }
        {
            int l = 512 + (BN == 256 ? tid : (tid & 255));  // cells 512..(BN*4-1)
            int kg = l / BN, row = l % BN;
            gload_lds16(Bp + (bcol + row) * (long)lda + kt + kg * 8, &Bs[buf][kg][row][0]);
        }
    };

    const int NT = Klen / 32;
    f32x4 acc[8][NR] = {};

    stageA(0); stageB(0);

    for (int T = 0; T < NT; ++T) {
        const int cur = T & 1;
        if (T + 1 < NT) {
            stageA(T + 1); stageB(T + 1);       // into buf cur^1 (reads done at T-1 end barrier)
            asm volatile("s_waitcnt vmcnt(4)" ::: "memory");   // tile T landed; T+1 in flight
        } else {
            asm volatile("s_waitcnt vmcnt(0)" ::: "memory");
        }
        __builtin_amdgcn_s_barrier();          // tile T visible to all waves
        asm volatile("" ::: "memory");

        bf16x8 bfv[NR], af[4];
#pragma unroll
        for (int n = 0; n < NR; ++n)
            bfv[n] = *(const bf16x8*)(&Bs[cur][lg][wc * WCOL + n * 16 + lr][0]);
#pragma unroll
        for (int m = 0; m < 4; ++m)
            af[m] = *(const bf16x8*)(&As[cur][lg][wr * 128 + m * 16 + lr][0]);
        asm volatile("s_waitcnt lgkmcnt(0)" ::: "memory");
        __builtin_amdgcn_sched_barrier(0);
        __builtin_amdgcn_s_setprio(1);
#pragma unroll
        for (int m = 0; m < 4; ++m)
#pragma unroll
            for (int n = 0; n < NR; ++n)
                acc[m][n] = __builtin_amdgcn_mfma_f32_16x16x32_bf16(af[m], bfv[n], acc[m][n], 0, 0, 0);
        __builtin_amdgcn_s_setprio(0);

        bf16x8 af2[4];
#pragma unroll
        for (int m = 0; m < 4; ++m)
            af2[m] = *(const bf16x8*)(&As[cur][lg][wr * 128 + (4 + m) * 16 + lr][0]);
        asm volatile("" ::: "memory");
        __builtin_amdgcn_s_barrier();
        asm volatile("s_waitcnt lgkmcnt(0)" ::: "memory");
        __builtin_amdgcn_sched_barrier(0);
        __builtin_amdgcn_s_setprio(1);
#pragma unroll
        for (int m = 0; m < 4; ++m)
#pragma unroll
            for (int n = 0; n < NR; ++n)
                acc[4 + m][n] = __builtin_amdgcn_mfma_f32_16x16x32_bf16(af2[m], bfv[n], acc[4 + m][n], 0, 0, 0);
        __builtin_amdgcn_s_setprio(0);
        asm volatile("" ::: "memory");
        __builtin_amdgcn_s_barrier();          // tile end: buf[cur] reusable
    }

#pragma unroll
    for (int m = 0; m < 8; ++m) {
#pragma unroll
        for (int n = 0; n < NR; ++n) {
            long gcol = bcol + wc * WCOL + n * 16 + lr;
            float bv = biasp ? biasp[gcol] : 0.f;
#pragma unroll
            for (int r = 0; r < 4; ++r) {
                long grow = brow + wr * 128 + m * 16 + lg * 4 + r;
                float v = acc[m][n][r] + bv;
                if (relu) v = v > 0.f ? v : 0.f;
                if (Cfp) Cfp[grow * N + gcol] = v;
                if (Ch) Ch[grow * N + gcol] = (bf16)v;
            }
        }
    }
}

// ---------------- flash attention (r11 best: defer-max, max3 tree, exp2-asm) ----------------
__global__ __launch_bounds__(256, 3)
void attn_fwd(const bf16* __restrict__ qkv, const bf16* __restrict__ vt,
              bf16* __restrict__ attn_o) {
    __shared__ bf16 Ks[2][64][64];   // [buf][kv][d], swizzled
    __shared__ bf16 Vs[2][64][64];   // [buf][d][kv], swizzled
    __shared__ bf16 Plds[4][16][64]; // per-wave P tile [q][kv], swizzled
    const int tid = threadIdx.x, lane = tid & 63, w = tid >> 6;
    const int lr = lane & 15, lg = lane >> 4;

    unsigned nwg = gridDim.x * gridDim.y;       // 1024
    unsigned wg = blockIdx.y * gridDim.x + blockIdx.x;
    unsigned cpx = nwg >> 3;
    unsigned swzid = (wg & 7) * cpx + (wg >> 3);
    const int bx = swzid % gridDim.x, bh = swzid / gridDim.x;
    const int b = bh >> 4, h = bh & 15;
    const int q0 = bx * 128 + w * 32;

    const bf16* Q  = qkv + (long)b * SEQL * 3072 + h * DKH;
    const bf16* Kp = qkv + (long)b * SEQL * 3072 + DM + h * DKH;
    const bf16* Vp = vt + (long)bh * DKH * SEQL;

    const int r0 = w * 8 + (lane >> 3);
    const int cbb = ((lane & 7) * 16) ^ ((r0 & 7) << 4);
    const int cb = cbb >> 1;

    auto stage = [&](int buf, int j0) {
#pragma unroll
        for (int c = 0; c < 2; ++c) {
            bf16* kd = &Ks[buf][0][0] + c * 2048 + w * 512 + lane * 8;
            bf16* vd = &Vs[buf][0][0] + c * 2048 + w * 512 + lane * 8;
            gload_lds16(Kp + (long)(j0 + c * 32 + r0) * 3072 + cb, kd);
            gload_lds16(Vp + (long)(c * 32 + r0) * SEQL + j0 + cb, vd);
        }
    };

    stage(0, 0);

    // Q pre-scale: (1/sqrt(64)) * log2(e) -> scores land in log2 domain
    const float QSC = 0.125f * 1.44269504f;
    bf16x8 aq[2][2];
#pragma unroll
    for (int a = 0; a < 2; ++a)
#pragma unroll
        for (int kh = 0; kh < 2; ++kh) {
            bf16x8 q = *(const bf16x8*)(Q + (long)(q0 + a * 16 + lr) * 3072 + kh * 32 + lg * 8);
#pragma unroll
            for (int e = 0; e < 8; ++e) q[e] = (bf16)((float)q[e] * QSC);
            aq[a][kh] = q;
        }

    float mrow[2] = {-1e30f, -1e30f};
    float lrow[2] = {0.f, 0.f};
    f32x4 accO[2][4] = {};
    char* pbase = (char*)&Plds[w][0][0];
    const int psw = (lr & 7) << 4;
    const f32x4 zero = {0.f, 0.f, 0.f, 0.f};
    int cur = 0;

    for (int it = 0; it < SEQL / 64; ++it) {
        if (it < SEQL / 64 - 1) {
            stage(cur ^ 1, (it + 1) * 64);
            asm volatile("s_waitcnt vmcnt(4)" ::: "memory");
        } else {
            asm volatile("s_waitcnt vmcnt(0)" ::: "memory");
        }
        __builtin_amdgcn_s_barrier();
        asm volatile("" ::: "memory");

        const char* Kbuf = (const char*)&Ks[cur][0][0];
        const char* Vbuf = (const char*)&Vs[cur][0][0];

        bf16x8 kf[4][2];
#pragma unroll
        for (int jh = 0; jh < 4; ++jh) {
            int row = jh * 16 + lr;
            int sw = (row & 7) << 4;
            kf[jh][0] = *(const bf16x8*)(Kbuf + row * 128 + ((lg * 16) ^ sw));
            kf[jh][1] = *(const bf16x8*)(Kbuf + row * 128 + ((64 + lg * 16) ^ sw));
        }
        bf16x8 vf[4][2];
#pragma unroll
        for (int c = 0; c < 4; ++c) {
            int row = c * 16 + lr;
            int sw = (row & 7) << 4;
            vf[c][0] = *(const bf16x8*)(Vbuf + row * 128 + ((lg * 16) ^ sw));
            vf[c][1] = *(const bf16x8*)(Vbuf + row * 128 + ((64 + lg * 16) ^ sw));
        }

#pragma unroll
        for (int a = 0; a < 2; ++a) {
            f32x4 s[4];
#pragma unroll
            for (int jh = 0; jh < 4; ++jh) {
                f32x4 t = __builtin_amdgcn_mfma_f32_16x16x32_bf16(kf[jh][0], aq[a][0], zero, 0, 0, 0);
                s[jh] = __builtin_amdgcn_mfma_f32_16x16x32_bf16(kf[jh][1], aq[a][1], t, 0, 0, 0);
            }
            // max over 16 lane-local values as a max3-friendly tree (v_max3_f32)
            float m0 = fmaxf(fmaxf(s[0][0], s[0][1]), fmaxf(s[0][2], s[0][3]));
            float m1 = fmaxf(fmaxf(s[1][0], s[1][1]), fmaxf(s[1][2], s[1][3]));
            float m2 = fmaxf(fmaxf(s[2][0], s[2][1]), fmaxf(s[2][2], s[2][3]));
            float m3 = fmaxf(fmaxf(s[3][0], s[3][1]), fmaxf(s[3][2], s[3][3]));
            float pm = fmaxf(fmaxf(m0, m1), fmaxf(m2, m3));
            pm = fmaxf(pm, __shfl_xor(pm, 16));
            pm = fmaxf(pm, __shfl_xor(pm, 32));
            // T13 defer-max: if max growth <= 8 (log2 domain, factor 256), keep
            // old mrow -> skip al exp, alr broadcast, and accO rescale entirely.
            int skip = __all(pm - mrow[a] <= 8.0f);
            if (!skip) {
                float mnew = fmaxf(mrow[a], pm);
                float al = fast_exp2(mrow[a] - mnew);
                mrow[a] = mnew;
                lrow[a] *= al;
                float alr[4];
#pragma unroll
                for (int r = 0; r < 4; ++r)
                    alr[r] = __shfl(al, (lane & 48) | (lg * 4 + r));
#pragma unroll
                for (int c = 0; c < 4; ++c)
#pragma unroll
                    for (int r = 0; r < 4; ++r) accO[a][c][r] *= alr[r];
            }
            float mcur = mrow[a];
            float psum = 0.f;
#pragma unroll
            for (int jh = 0; jh < 4; ++jh)
#pragma unroll
                for (int r = 0; r < 4; ++r) {
                    float p = fast_exp2(s[jh][r] - mcur);
                    s[jh][r] = p;
                    psum += p;
                }
            psum += __shfl_xor(psum, 16);
            psum += __shfl_xor(psum, 32);
            lrow[a] += psum;
#pragma unroll
            for (int jh = 0; jh < 4; ++jh) {
                bf16x4 pw = {(bf16)s[jh][0], (bf16)s[jh][1], (bf16)s[jh][2], (bf16)s[jh][3]};
                *(bf16x4*)(pbase + lr * 128 + ((jh * 32 + lg * 8) ^ psw)) = pw;
            }
            bf16x8 pa[2];
#pragma unroll
            for (int i = 0; i < 2; ++i)
                pa[i] = *(const bf16x8*)(pbase + lr * 128 + ((i * 64 + lg * 16) ^ psw));
#pragma unroll
            for (int c = 0; c < 4; ++c) {
                accO[a][c] = __builtin_amdgcn_mfma_f32_16x16x32_bf16(pa[0], vf[c][0], accO[a][c], 0, 0, 0);
                accO[a][c] = __builtin_amdgcn_mfma_f32_16x16x32_bf16(pa[1], vf[c][1], accO[a][c], 0, 0, 0);
            }
        }
        asm volatile("" ::: "memory");
        __builtin_amdgcn_s_barrier();
        cur ^= 1;
    }

#pragma unroll
    for (int a = 0; a < 2; ++a) {
        float linv = 1.0f / lrow[a];
        float invr[4];
#pragma unroll
        for (int r = 0; r < 4; ++r)
            invr[r] = __shfl(linv, (lane & 48) | (lg * 4 + r));
#pragma unroll
        for (int r = 0; r < 4; ++r) {
            long grow = (long)b * SEQL + q0 + a * 16 + lg * 4 + r;
#pragma unroll
            for (int c = 0; c < 4; ++c)
                attn_o[grow * DM + h * DKH + c * 16 + lr] = (bf16)(accO[a][c][r] * invr[r]);
        }
    }
}

// ---------------- fused residual add (+ optional 3rd input) + LayerNorm ----------------
__global__ __launch_bounds__(256)
void add_ln(const float* __restrict__ A, const float* __restrict__ B,
            const float* __restrict__ B2,
            const float* __restrict__ g, const float* __restrict__ be,
            float* __restrict__ outf, bf16* __restrict__ outh) {
    const int w = threadIdx.x >> 6, lane = threadIdx.x & 63;
    const long row = (long)blockIdx.x * 4 + w;
    const float4* pa = (const float4*)(A + row * DM);
    const float4* pb = (const float4*)(B + row * DM);
    const float4* pb2 = B2 ? (const float4*)(B2 + row * DM) : nullptr;
    float4 v[4];
    float s = 0.f;
#pragma unroll
    for (int i = 0; i < 4; ++i) {
        float4 a = pa[i * 64 + lane], bb = pb[i * 64 + lane];
        v[i] = make_float4(a.x + bb.x, a.y + bb.y, a.z + bb.z, a.w + bb.w);
        if (pb2) {
            float4 b2 = pb2[i * 64 + lane];
            v[i].x += b2.x; v[i].y += b2.y; v[i].z += b2.z; v[i].w += b2.w;
        }
        s += v[i].x + v[i].y + v[i].z + v[i].w;
    }
#pragma unroll
    for (int off = 32; off; off >>= 1) s += __shfl_xor(s, off);
    float mu = s * (1.0f / 1024.0f);
    float var = 0.f;
#pragma unroll
    for (int i = 0; i < 4; ++i) {
        float dx = v[i].x - mu, dy = v[i].y - mu, dz = v[i].z - mu, dw = v[i].w - mu;
        var += dx * dx + dy * dy + dz * dz + dw * dw;
    }
#pragma unroll
    for (int off = 32; off; off >>= 1) var += __shfl_xor(var, off);
    float rs = 1.0f / sqrtf(var * (1.0f / 1024.0f) + 1e-5f);
    const float4* pg = (const float4*)g;
    const float4* pe = (const float4*)be;
#pragma unroll
    for (int i = 0; i < 4; ++i) {
        float4 gg = pg[i * 64 + lane], ee = pe[i * 64 + lane];
        float4 o = make_float4((v[i].x - mu) * rs * gg.x + ee.x,
                               (v[i].y - mu) * rs * gg.y + ee.y,
                               (v[i].z - mu) * rs * gg.z + ee.z,
                               (v[i].w - mu) * rs * gg.w + ee.w);
        if (outf) ((float4*)(outf + row * DM))[i * 64 + lane] = o;
        if (outh) {
            bf16x4 ho = {(bf16)o.x, (bf16)o.y, (bf16)o.z, (bf16)o.w};
            *(bf16x4*)(outh + row * DM + (i * 64 + lane) * 4) = ho;
        }
    }
}

extern "C" void kernel_launch(void* const* d_in, const int* in_sizes, int n_in,
                              void* d_out, int out_size, void* d_ws, size_t ws_size,
                              hipStream_t stream) {
    const float* x   = (const float*)d_in[0];
    const float* Wq  = (const float*)d_in[1];
    const float* bq  = (const float*)d_in[2];
    const float* Wk  = (const float*)d_in[3];
    const float* bk  = (const float*)d_in[4];
    const float* Wv  = (const float*)d_in[5];
    const float* bv  = (const float*)d_in[6];
    const float* Wo  = (const float*)d_in[7];
    const float* bo  = (const float*)d_in[8];
    const float* W1  = (const float*)d_in[9];
    const float* b1  = (const float*)d_in[10];
    const float* W2  = (const float*)d_in[11];
    const float* b2  = (const float*)d_in[12];
    const float* g1  = (const float*)d_in[13];
    const float* be1 = (const float*)d_in[14];
    const float* g2  = (const float*)d_in[15];
    const float* be2 = (const float*)d_in[16];
    float* out = (float*)d_out;

    char* ws = (char*)d_ws;
    size_t off = 0;
    auto alloc = [&](size_t bytes) {
        void* p = ws + off;
        off += (bytes + 255) & ~(size_t)255;
        return p;
    };
    bf16* xh    = (bf16*)alloc((size_t)NTOK * DM * 2);
    bf16* wqkvt = (bf16*)alloc((size_t)3072 * 1024 * 2);
    bf16* wot   = (bf16*)alloc((size_t)1024 * 1024 * 2);
    bf16* w1t   = (bf16*)alloc((size_t)4096 * 1024 * 2);
    bf16* w2t   = (bf16*)alloc((size_t)1024 * 4096 * 2);
    float* bqkv = (float*)alloc((size_t)3072 * 4);
    bf16* qkv   = (bf16*)alloc((size_t)NTOK * 3072 * 2);
    bf16* vtb   = (bf16*)alloc((size_t)NTOK * DM * 2);
    bf16* attno = (bf16*)alloc((size_t)NTOK * DM * 2);
    float* projf  = (float*)alloc((size_t)NTOK * DM * 4);  // split-K partial 0
    float* projf1 = (float*)alloc((size_t)NTOK * DM * 4);  // split-K partial 1
    float* x1f  = (float*)alloc((size_t)NTOK * DM * 4);
    bf16* x1h   = (bf16*)alloc((size_t)NTOK * DM * 2);
    bf16* ffh   = (bf16*)qkv; // alias: qkv+vtb dead after attn; 67MB for [8192][4096]

    dim3 tb(32, 8);
    cast_f32_bf16<<<2048, 256, 0, stream>>>(x, xh, (long)NTOK * DM);
    transpose_cast<<<dim3(32, 32), tb, 0, stream>>>(Wq, wqkvt, 1024, 1024);
    transpose_cast<<<dim3(32, 32), tb, 0, stream>>>(Wk, wqkvt + (size_t)1024 * 1024, 1024, 1024);
    transpose_cast<<<dim3(32, 32), tb, 0, stream>>>(Wv, wqkvt + (size_t)2048 * 1024, 1024, 1024);
    transpose_cast<<<dim3(32, 32), tb, 0, stream>>>(Wo, wot, 1024, 1024);
    transpose_cast<<<dim3(128, 32), tb, 0, stream>>>(W1, w1t, 1024, 4096);
    transpose_cast<<<dim3(32, 128), tb, 0, stream>>>(W2, w2t, 4096, 1024);
    concat3<<<12, 256, 0, stream>>>(bq, bk, bv, bqkv);

    // QKV: [8192,1024]@[1024,3072] -> bf16 (BN=192: grid 16x32=512 = 2 even rounds)
    gemm8p<192><<<dim3(3072 / 192, 8192 / 256, 1), 512, 0, stream>>>(
        xh, wqkvt, bqkv, nullptr, qkv, 3072, 1024, 1024, 0, 0);
    build_vt<<<dim3(SEQL / 32, 2, 64), tb, 0, stream>>>(qkv, vtb);
    attn_fwd<<<dim3(SEQL / 128, 64), 256, 0, stream>>>(qkv, vtb, attno);
    // Wo: split-K x2 (Klen=512), grid 4x32x2=256 -> projf/projf1 fp32
    gemm8p<256><<<dim3(1024 / 256, 8192 / 256, 2), 512, 0, stream>>>(
        attno, wot, bo, projf, nullptr, 1024, 1024, 512, 0, (long)NTOK * DM);
    add_ln<<<NTOK / 4, 256, 0, stream>>>(x, projf, projf1, g1, be1, x1f, x1h);
    // FFN1: [8192,1024]@[1024,4096]+ReLU -> bf16 (grid 16x32=512)
    gemm8p<256><<<dim3(4096 / 256, 8192 / 256, 1), 512, 0, stream>>>(
        x1h, w1t, b1, nullptr, ffh, 4096, 1024, 1024, 1, 0);
    // FFN2: split-K x2 (Klen=2048), grid 4x32x2=256 -> projf/projf1
    gemm8p<256><<<dim3(1024 / 256, 8192 / 256, 2), 512, 0, stream>>>(
        ffh, w2t, b2, projf, nullptr, 1024, 4096, 2048, 0, (long)NTOK * DM);
    add_ln<<<NTOK / 4, 256, 0, stream>>>(x1f, projf, projf1, g2, be2, out, nullptr);
}

// Round 14
// 550.500 us; speedup vs baseline: 2.8757x; 2.8757x over previous
//
#include <hip/hip_runtime.h>

typedef __bf16 bf16;
typedef __bf16 bf16x4 __attribute__((ext_vector_type(4)));
typedef __bf16 bf16x8 __attribute__((ext_vector_type(8)));
typedef float  f32x4  __attribute__((ext_vector_type(4)));

#define DM   1024
#define NH   16
#define DKH  64
#define DFF  4096
#define SEQL 2048
#define NTOK 8192

typedef __attribute__((address_space(1))) void GAS;
typedef __attribute__((address_space(3))) void LAS;

__device__ inline void gload_lds16(const void* g, void* l) {
    __builtin_amdgcn_global_load_lds((GAS*)g, (LAS*)l, 16, 0, 0);
}

// bare v_exp_f32 (exp2) — avoids libm exp2f's range-check sequence
__device__ inline float fast_exp2(float x) {
    float r;
    asm("v_exp_f32 %0, %1" : "=v"(r) : "v"(x));
    return r;
}

// ---------------- cast f32 -> bf16 ----------------
__global__ void cast_f32_bf16(const float* __restrict__ in, bf16* __restrict__ out, long n) {
    long i = ((long)blockIdx.x * 256 + threadIdx.x) * 4;
    long stride = (long)gridDim.x * 256 * 4;
    for (; i < n; i += stride) {
        float4 v = *(const float4*)(in + i);
        bf16x4 o = {(bf16)v.x, (bf16)v.y, (bf16)v.z, (bf16)v.w};
        *(bf16x4*)(out + i) = o;
    }
}

// ---------------- transpose + cast: src[R][C] f32 -> dst[C][R] bf16 ----------------
__global__ void transpose_cast(const float* __restrict__ src, bf16* __restrict__ dst, int R, int C) {
    __shared__ float t[32][33];
    int c0 = blockIdx.x * 32, r0 = blockIdx.y * 32;
    int tx = threadIdx.x, ty = threadIdx.y; // block (32,8)
#pragma unroll
    for (int i = 0; i < 4; ++i)
        t[ty + i * 8][tx] = src[(long)(r0 + ty + i * 8) * C + c0 + tx];
    __syncthreads();
#pragma unroll
    for (int i = 0; i < 4; ++i)
        dst[(long)(c0 + ty + i * 8) * R + r0 + tx] = (bf16)t[tx][ty + i * 8];
}

// ---------------- concat 3 bias vectors (1024 each) ----------------
__global__ void concat3(const float* __restrict__ a, const float* __restrict__ b,
                        const float* __restrict__ c, float* __restrict__ out) {
    int i = blockIdx.x * 256 + threadIdx.x;
    if (i < 1024) out[i] = a[i];
    else if (i < 2048) out[i] = b[i - 1024];
    else if (i < 3072) out[i] = c[i - 2048];
}

// ---------------- build V^T: vt[(b*16+h)*64 + d][s] ----------------
__global__ void build_vt(const bf16* __restrict__ qkv, bf16* __restrict__ vt) {
    __shared__ bf16 t[32][33];
    int bh = blockIdx.z, b = bh >> 4, h = bh & 15;
    int s0 = blockIdx.x * 32, d0 = blockIdx.y * 32;
    int tx = threadIdx.x, ty = threadIdx.y;
#pragma unroll
    for (int i = 0; i < 4; ++i)
        t[ty + i * 8][tx] = qkv[(long)(b * SEQL + s0 + ty + i * 8) * 3072 + 2 * DM + h * DKH + d0 + tx];
    __syncthreads();
#pragma unroll
    for (int i = 0; i < 4; ++i)
        vt[((long)bh * DKH + d0 + ty + i * 8) * SEQL + s0 + tx] = (bf16)t[tx][ty + i * 8];
}

// ---------------- GEMM (round-12 best config, verbatim) ----------------
// 256xBN tile, 8 waves (2Mx4N, wave=128x(BN/4)), BK=32 K-tiles, 4 LDS buffers,
// depth-3 staging in 2-load bursts, counted vmcnt ladder, setprio+sched_barrier.
// BN=192: j=1 B-stage duplicates cells 512..767 on threads 256..511 (benign
// same-value LDS writes) so every thread issues exactly 4 loads/tile.
// Split-K via blockIdx.z; bias applied only by z==0 (partials summed in add_ln).
template<int BN>
__global__ __launch_bounds__(512, 2)
void gemm8p(const bf16* __restrict__ A, const bf16* __restrict__ Bt,
            const float* __restrict__ bias,
            float* __restrict__ Cf, bf16* __restrict__ Ch,
            int N, int lda, int Klen, int relu, long strideCf) {
    constexpr int NR = BN / 64;            // 256->4, 192->3
    constexpr int WCOL = BN / 4;           // per-wave N extent
    __shared__ bf16 As[4][4][256][8];
    __shared__ bf16 Bs[4][4][BN][8];
    const int tid = threadIdx.x;
    const int lane = tid & 63;
    const int wv = tid >> 6;
    const int wr = wv >> 2, wc = wv & 3;      // 2 x 4 wave grid
    const int lr = lane & 15, lg = lane >> 4;

    unsigned gx = gridDim.x, gy = gridDim.y;
    unsigned nwg = gx * gy * gridDim.z;
    unsigned wg = (blockIdx.z * gy + blockIdx.y) * gx + blockIdx.x;
    unsigned swz = (wg & 7) * (nwg >> 3) + (wg >> 3);
    unsigned bxi = swz % gx;
    unsigned rem2 = swz / gx;
    unsigned byi = rem2 % gy, bzi = rem2 / gy;

    const long brow = (long)byi * 256;
    const long bcol = (long)bxi * BN;
    const bf16* Ap = A + (long)bzi * Klen;
    const bf16* Bp = Bt + (long)bzi * Klen;
    float* Cfp = Cf ? Cf + (long)bzi * strideCf : nullptr;
    const float* biasp = (bzi == 0) ? bias : nullptr;

    auto stageA = [&](int X) {
        const int kt = X * 32, buf = X & 3;
#pragma unroll
        for (int j = 0; j < 2; ++j) {
            int l = j * 512 + tid;
            int kg = l >> 8, row = l & 255;
            gload_lds16(Ap + (brow + row) * (long)lda + kt + kg * 8, &As[buf][kg][row][0]);
        }
    };
    auto stageB = [&](int X) {
        const int kt = X * 32, buf = X & 3;
        {
            int l = tid;                       // cells 0..511
            int kg = l / BN, row = l % BN;
            gload_lds16(Bp + (bcol + row) * (long)lda + kt + kg * 8, &Bs[buf][kg][row][0]);
        }
        {
            int l = 512 + (BN == 256 ? tid : (tid & 255));  // cells 512..(BN*4-1)
            int kg = l / BN, row = l % BN;
            gload_lds16(Bp + (bcol + row) * (long)lda + kt + kg * 8, &Bs[buf][kg][row][0]);
        }
    };

    const int NT = Klen / 32;
    f32x4 acc[8][NR] = {};

    for (int p = 0; p < 3 && p < NT; ++p) { stageA(p); stageB(p); }

    for (int T = 0; T < NT; ++T) {
        const int cur = T & 3;
        if (T + 3 < NT) stageA(T + 3);
        if (T + 3 < NT)      asm volatile("s_waitcnt vmcnt(10)" ::: "memory");
        else if (T + 2 < NT) asm volatile("s_waitcnt vmcnt(8)"  ::: "memory");
        else if (T + 1 < NT) asm volatile("s_waitcnt vmcnt(4)"  ::: "memory");
        else                 asm volatile("s_waitcnt vmcnt(0)"  ::: "memory");
        __builtin_amdgcn_s_barrier();          // tile T visible to all waves
        asm volatile("" ::: "memory");

        bf16x8 bfv[NR], af[4];
#pragma unroll
        for (int n = 0; n < NR; ++n)
            bfv[n] = *(const bf16x8*)(&Bs[cur][lg][wc * WCOL + n * 16 + lr][0]);
#pragma unroll
        for (int m = 0; m < 4; ++m)
            af[m] = *(const bf16x8*)(&As[cur][lg][wr * 128 + m * 16 + lr][0]);
        asm volatile("s_waitcnt lgkmcnt(0)" ::: "memory");
        __builtin_amdgcn_sched_barrier(0);
        __builtin_amdgcn_s_setprio(1);
#pragma unroll
        for (int m = 0; m < 4; ++m)
#pragma unroll
            for (int n = 0; n < NR; ++n)
                acc[m][n] = __builtin_amdgcn_mfma_f32_16x16x32_bf16(af[m], bfv[n], acc[m][n], 0, 0, 0);
        __builtin_amdgcn_s_setprio(0);

        bf16x8 af2[4];
#pragma unroll
        for (int m = 0; m < 4; ++m)
            af2[m] = *(const bf16x8*)(&As[cur][lg][wr * 128 + (4 + m) * 16 + lr][0]);
        if (T + 3 < NT) stageB(T + 3);
        asm volatile("" ::: "memory");
        __builtin_amdgcn_s_barrier();
        asm volatile("s_waitcnt lgkmcnt(0)" ::: "memory");
        __builtin_amdgcn_sched_barrier(0);
        __builtin_amdgcn_s_setprio(1);
#pragma unroll
        for (int m = 0; m < 4; ++m)
#pragma unroll
            for (int n = 0; n < NR; ++n)
                acc[4 + m][n] = __builtin_amdgcn_mfma_f32_16x16x32_bf16(af2[m], bfv[n], acc[4 + m][n], 0, 0, 0);
        __builtin_amdgcn_s_setprio(0);
        asm volatile("" ::: "memory");
        __builtin_amdgcn_s_barrier();
    }

#pragma unroll
    for (int m = 0; m < 8; ++m) {
#pragma unroll
        for (int n = 0; n < NR; ++n) {
            long gcol = bcol + wc * WCOL + n * 16 + lr;
            float bv = biasp ? biasp[gcol] : 0.f;
#pragma unroll
            for (int r = 0; r < 4; ++r) {
                long grow = brow + wr * 128 + m * 16 + lg * 4 + r;
                float v = acc[m][n][r] + bv;
                if (relu) v = v > 0.f ? v : 0.f;
                if (Cfp) Cfp[grow * N + gcol] = v;
                if (Ch) Ch[grow * N + gcol] = (bf16)v;
            }
        }
    }
}

// ---------------- flash attention (r11/r12 best: defer-max, max3 tree, exp2-asm) ----------------
__global__ __launch_bounds__(256, 3)
void attn_fwd(const bf16* __restrict__ qkv, const bf16* __restrict__ vt,
              bf16* __restrict__ attn_o) {
    __shared__ bf16 Ks[2][64][64];   // [buf][kv][d], swizzled
    __shared__ bf16 Vs[2][64][64];   // [buf][d][kv], swizzled
    __shared__ bf16 Plds[4][16][64]; // per-wave P tile [q][kv], swizzled
    const int tid = threadIdx.x, lane = tid & 63, w = tid >> 6;
    const int lr = lane & 15, lg = lane >> 4;

    unsigned nwg = gridDim.x * gridDim.y;       // 1024
    unsigned wg = blockIdx.y * gridDim.x + blockIdx.x;
    unsigned cpx = nwg >> 3;
    unsigned swzid = (wg & 7) * cpx + (wg >> 3);
    const int bx = swzid % gridDim.x, bh = swzid / gridDim.x;
    const int b = bh >> 4, h = bh & 15;
    const int q0 = bx * 128 + w * 32;

    const bf16* Q  = qkv + (long)b * SEQL * 3072 + h * DKH;
    const bf16* Kp = qkv + (long)b * SEQL * 3072 + DM + h * DKH;
    const bf16* Vp = vt + (long)bh * DKH * SEQL;

    const int r0 = w * 8 + (lane >> 3);
    const int cbb = ((lane & 7) * 16) ^ ((r0 & 7) << 4);
    const int cb = cbb >> 1;

    auto stage = [&](int buf, int j0) {
#pragma unroll
        for (int c = 0; c < 2; ++c) {
            bf16* kd = &Ks[buf][0][0] + c * 2048 + w * 512 + lane * 8;
            bf16* vd = &Vs[buf][0][0] + c * 2048 + w * 512 + lane * 8;
            gload_lds16(Kp + (long)(j0 + c * 32 + r0) * 3072 + cb, kd);
            gload_lds16(Vp + (long)(c * 32 + r0) * SEQL + j0 + cb, vd);
        }
    };

    stage(0, 0);

    // Q pre-scale: (1/sqrt(64)) * log2(e) -> scores land in log2 domain
    const float QSC = 0.125f * 1.44269504f;
    bf16x8 aq[2][2];
#pragma unroll
    for (int a = 0; a < 2; ++a)
#pragma unroll
        for (int kh = 0; kh < 2; ++kh) {
            bf16x8 q = *(const bf16x8*)(Q + (long)(q0 + a * 16 + lr) * 3072 + kh * 32 + lg * 8);
#pragma unroll
            for (int e = 0; e < 8; ++e) q[e] = (bf16)((float)q[e] * QSC);
            aq[a][kh] = q;
        }

    float mrow[2] = {-1e30f, -1e30f};
    float lrow[2] = {0.f, 0.f};
    f32x4 accO[2][4] = {};
    char* pbase = (char*)&Plds[w][0][0];
    const int psw = (lr & 7) << 4;
    const f32x4 zero = {0.f, 0.f, 0.f, 0.f};
    int cur = 0;

    for (int it = 0; it < SEQL / 64; ++it) {
        if (it < SEQL / 64 - 1) {
            stage(cur ^ 1, (it + 1) * 64);
            asm volatile("s_waitcnt vmcnt(4)" ::: "memory");
        } else {
            asm volatile("s_waitcnt vmcnt(0)" ::: "memory");
        }
        __builtin_amdgcn_s_barrier();
        asm volatile("" ::: "memory");

        const char* Kbuf = (const char*)&Ks[cur][0][0];
        const char* Vbuf = (const char*)&Vs[cur][0][0];

        bf16x8 kf[4][2];
#pragma unroll
        for (int jh = 0; jh < 4; ++jh) {
            int row = jh * 16 + lr;
            int sw = (row & 7) << 4;
            kf[jh][0] = *(const bf16x8*)(Kbuf + row * 128 + ((lg * 16) ^ sw));
            kf[jh][1] = *(const bf16x8*)(Kbuf + row * 128 + ((64 + lg * 16) ^ sw));
        }
        bf16x8 vf[4][2];
#pragma unroll
        for (int c = 0; c < 4; ++c) {
            int row = c * 16 + lr;
            int sw = (row & 7) << 4;
            vf[c][0] = *(const bf16x8*)(Vbuf + row * 128 + ((lg * 16) ^ sw));
            vf[c][1] = *(const bf16x8*)(Vbuf + row * 128 + ((64 + lg * 16) ^ sw));
        }

#pragma unroll
        for (int a = 0; a < 2; ++a) {
            f32x4 s[4];
#pragma unroll
            for (int jh = 0; jh < 4; ++jh) {
                f32x4 t = __builtin_amdgcn_mfma_f32_16x16x32_bf16(kf[jh][0], aq[a][0], zero, 0, 0, 0);
                s[jh] = __builtin_amdgcn_mfma_f32_16x16x32_bf16(kf[jh][1], aq[a][1], t, 0, 0, 0);
            }
            // max over 16 lane-local values as a max3-friendly tree (v_max3_f32)
            float m0 = fmaxf(fmaxf(s[0][0], s[0][1]), fmaxf(s[0][2], s[0][3]));
            float m1 = fmaxf(fmaxf(s[1][0], s[1][1]), fmaxf(s[1][2], s[1][3]));
            float m2 = fmaxf(fmaxf(s[2][0], s[2][1]), fmaxf(s[2][2], s[2][3]));
            float m3 = fmaxf(fmaxf(s[3][0], s[3][1]), fmaxf(s[3][2], s[3][3]));
            float pm = fmaxf(fmaxf(m0, m1), fmaxf(m2, m3));
            pm = fmaxf(pm, __shfl_xor(pm, 16));
            pm = fmaxf(pm, __shfl_xor(pm, 32));
            // T13 defer-max: if max growth <= 8 (log2 domain, factor 256), keep
            // old mrow -> skip al exp, alr broadcast, and accO rescale entirely.
            int skip = __all(pm - mrow[a] <= 8.0f);
            if (!skip) {
                float mnew = fmaxf(mrow[a], pm);
                float al = fast_exp2(mrow[a] - mnew);
                mrow[a] = mnew;
                lrow[a] *= al;
                float alr[4];
#pragma unroll
                for (int r = 0; r < 4; ++r)
                    alr[r] = __shfl(al, (lane & 48) | (lg * 4 + r));
#pragma unroll
                for (int c = 0; c < 4; ++c)
#pragma unroll
                    for (int r = 0; r < 4; ++r) accO[a][c][r] *= alr[r];
            }
            float mcur = mrow[a];
            float psum = 0.f;
#pragma unroll
            for (int jh = 0; jh < 4; ++jh)
#pragma unroll
                for (int r = 0; r < 4; ++r) {
                    float p = fast_exp2(s[jh][r] - mcur);
                    s[jh][r] = p;
                    psum += p;
                }
            psum += __shfl_xor(psum, 16);
            psum += __shfl_xor(psum, 32);
            lrow[a] += psum;
#pragma unroll
            for (int jh = 0; jh < 4; ++jh) {
                bf16x4 pw = {(bf16)s[jh][0], (bf16)s[jh][1], (bf16)s[jh][2], (bf16)s[jh][3]};
                *(bf16x4*)(pbase + lr * 128 + ((jh * 32 + lg * 8) ^ psw)) = pw;
            }
            bf16x8 pa[2];
#pragma unroll
            for (int i = 0; i < 2; ++i)
                pa[i] = *(const bf16x8*)(pbase + lr * 128 + ((i * 64 + lg * 16) ^ psw));
#pragma unroll
            for (int c = 0; c < 4; ++c) {
                accO[a][c] = __builtin_amdgcn_mfma_f32_16x16x32_bf16(pa[0], vf[c][0], accO[a][c], 0, 0, 0);
                accO[a][c] = __builtin_amdgcn_mfma_f32_16x16x32_bf16(pa[1], vf[c][1], accO[a][c], 0, 0, 0);
            }
        }
        asm volatile("" ::: "memory");
        __builtin_amdgcn_s_barrier();
        cur ^= 1;
    }

#pragma unroll
    for (int a = 0; a < 2; ++a) {
        float linv = 1.0f / lrow[a];
        float invr[4];
#pragma unroll
        for (int r = 0; r < 4; ++r)
            invr[r] = __shfl(linv, (lane & 48) | (lg * 4 + r));
#pragma unroll
        for (int r = 0; r < 4; ++r) {
            long grow = (long)b * SEQL + q0 + a * 16 + lg * 4 + r;
#pragma unroll
            for (int c = 0; c < 4; ++c)
                attn_o[grow * DM + h * DKH + c * 16 + lr] = (bf16)(accO[a][c][r] * invr[r]);
        }
    }
}

// ---------------- fused residual add (+ optional 3rd input) + LayerNorm ----------------
__global__ __launch_bounds__(256)
void add_ln(const float* __restrict__ A, const float* __restrict__ B,
            const float* __restrict__ B2,
            const float* __restrict__ g, const float* __restrict__ be,
            float* __restrict__ outf, bf16* __restrict__ outh) {
    const int w = threadIdx.x >> 6, lane = threadIdx.x & 63;
    const long row = (long)blockIdx.x * 4 + w;
    const float4* pa = (const float4*)(A + row * DM);
    const float4* pb = (const float4*)(B + row * DM);
    const float4* pb2 = B2 ? (const float4*)(B2 + row * DM) : nullptr;
    float4 v[4];
    float s = 0.f;
#pragma unroll
    for (int i = 0; i < 4; ++i) {
        float4 a = pa[i * 64 + lane], bb = pb[i * 64 + lane];
        v[i] = make_float4(a.x + bb.x, a.y + bb.y, a.z + bb.z, a.w + bb.w);
        if (pb2) {
            float4 b2 = pb2[i * 64 + lane];
            v[i].x += b2.x; v[i].y += b2.y; v[i].z += b2.z; v[i].w += b2.w;
        }
        s += v[i].x + v[i].y + v[i].z + v[i].w;
    }
#pragma unroll
    for (int off = 32; off; off >>= 1) s += __shfl_xor(s, off);
    float mu = s * (1.0f / 1024.0f);
    float var = 0.f;
#pragma unroll
    for (int i = 0; i < 4; ++i) {
        float dx = v[i].x - mu, dy = v[i].y - mu, dz = v[i].z - mu, dw = v[i].w - mu;
        var += dx * dx + dy * dy + dz * dz + dw * dw;
    }
#pragma unroll
    for (int off = 32; off; off >>= 1) var += __shfl_xor(var, off);
    float rs = 1.0f / sqrtf(var * (1.0f / 1024.0f) + 1e-5f);
    const float4* pg = (const float4*)g;
    const float4* pe = (const float4*)be;
#pragma unroll
    for (int i = 0; i < 4; ++i) {
        float4 gg = pg[i * 64 + lane], ee = pe[i * 64 + lane];
        float4 o = make_float4((v[i].x - mu) * rs * gg.x + ee.x,
                               (v[i].y - mu) * rs * gg.y + ee.y,
                               (v[i].z - mu) * rs * gg.z + ee.z,
                               (v[i].w - mu) * rs * gg.w + ee.w);
        if (outf) ((float4*)(outf + row * DM))[i * 64 + lane] = o;
        if (outh) {
            bf16x4 ho = {(bf16)o.x, (bf16)o.y, (bf16)o.z, (bf16)o.w};
            *(bf16x4*)(outh + row * DM + (i * 64 + lane) * 4) = ho;
        }
    }
}

extern "C" void kernel_launch(void* const* d_in, const int* in_sizes, int n_in,
                              void* d_out, int out_size, void* d_ws, size_t ws_size,
                              hipStream_t stream) {
    const float* x   = (const float*)d_in[0];
    const float* Wq  = (const float*)d_in[1];
    const float* bq  = (const float*)d_in[2];
    const float* Wk  = (const float*)d_in[3];
    const float* bk  = (const float*)d_in[4];
    const float* Wv  = (const float*)d_in[5];
    const float* bv  = (const float*)d_in[6];
    const float* Wo  = (const float*)d_in[7];
    const float* bo  = (const float*)d_in[8];
    const float* W1  = (const float*)d_in[9];
    const float* b1  = (const float*)d_in[10];
    const float* W2  = (const float*)d_in[11];
    const float* b2  = (const float*)d_in[12];
    const float* g1  = (const float*)d_in[13];
    const float* be1 = (const float*)d_in[14];
    const float* g2  = (const float*)d_in[15];
    const float* be2 = (const float*)d_in[16];
    float* out = (float*)d_out;

    char* ws = (char*)d_ws;
    size_t off = 0;
    auto alloc = [&](size_t bytes) {
        void* p = ws + off;
        off += (bytes + 255) & ~(size_t)255;
        return p;
    };
    bf16* xh    = (bf16*)alloc((size_t)NTOK * DM * 2);
    bf16* wqkvt = (bf16*)alloc((size_t)3072 * 1024 * 2);
    bf16* wot   = (bf16*)alloc((size_t)1024 * 1024 * 2);
    bf16* w1t   = (bf16*)alloc((size_t)4096 * 1024 * 2);
    bf16* w2t   = (bf16*)alloc((size_t)1024 * 4096 * 2);
    float* bqkv = (float*)alloc((size_t)3072 * 4);
    bf16* qkv   = (bf16*)alloc((size_t)NTOK * 3072 * 2);
    bf16* vtb   = (bf16*)alloc((size_t)NTOK * DM * 2);
    bf16* attno = (bf16*)alloc((size_t)NTOK * DM * 2);
    float* projf  = (float*)alloc((size_t)NTOK * DM * 4);  // split-K partial 0
    float* projf1 = (float*)alloc((size_t)NTOK * DM * 4);  // split-K partial 1
    float* x1f  = (float*)alloc((size_t)NTOK * DM * 4);
    bf16* x1h   = (bf16*)alloc((size_t)NTOK * DM * 2);
    bf16* ffh   = (bf16*)qkv; // alias: qkv+vtb dead after attn; 67MB for [8192][4096]

    dim3 tb(32, 8);
    cast_f32_bf16<<<2048, 256, 0, stream>>>(x, xh, (long)NTOK * DM);
    transpose_cast<<<dim3(32, 32), tb, 0, stream>>>(Wq, wqkvt, 1024, 1024);
    transpose_cast<<<dim3(32, 32), tb, 0, stream>>>(Wk, wqkvt + (size_t)1024 * 1024, 1024, 1024);
    transpose_cast<<<dim3(32, 32), tb, 0, stream>>>(Wv, wqkvt + (size_t)2048 * 1024, 1024, 1024);
    transpose_cast<<<dim3(32, 32), tb, 0, stream>>>(Wo, wot, 1024, 1024);
    transpose_cast<<<dim3(128, 32), tb, 0, stream>>>(W1, w1t, 1024, 4096);
    transpose_cast<<<dim3(32, 128), tb, 0, stream>>>(W2, w2t, 4096, 1024);
    concat3<<<12, 256, 0, stream>>>(bq, bk, bv, bqkv);

    // QKV: [8192,1024]@[1024,3072] -> bf16 (BN=192: grid 16x32=512 = 2 even rounds)
    gemm8p<192><<<dim3(3072 / 192, 8192 / 256, 1), 512, 0, stream>>>(
        xh, wqkvt, bqkv, nullptr, qkv, 3072, 1024, 1024, 0, 0);
    build_vt<<<dim3(SEQL / 32, 2, 64), tb, 0, stream>>>(qkv, vtb);
    attn_fwd<<<dim3(SEQL / 128, 64), 256, 0, stream>>>(qkv, vtb, attno);
    // Wo: split-K x2 (Klen=512), grid 4x32x2=256 -> projf/projf1 fp32
    gemm8p<256><<<dim3(1024 / 256, 8192 / 256, 2), 512, 0, stream>>>(
        attno, wot, bo, projf, nullptr, 1024, 1024, 512, 0, (long)NTOK * DM);
    add_ln<<<NTOK / 4, 256, 0, stream>>>(x, projf, projf1, g1, be1, x1f, x1h);
    // FFN1: [8192,1024]@[1024,4096]+ReLU -> bf16 (grid 16x32=512)
    gemm8p<256><<<dim3(4096 / 256, 8192 / 256, 1), 512, 0, stream>>>(
        x1h, w1t, b1, nullptr, ffh, 4096, 1024, 1024, 1, 0);
    // FFN2: split-K x2 (Klen=2048), grid 4x32x2=256 -> projf/projf1
    gemm8p<256><<<dim3(1024 / 256, 8192 / 256, 2), 512, 0, stream>>>(
        ffh, w2t, b2, projf, nullptr, 1024, 4096, 2048, 0, (long)NTOK * DM);
    add_ln<<<NTOK / 4, 256, 0, stream>>>(x1f, projf, projf1, g2, be2, out, nullptr);
}

// Round 15
// 511.161 us; speedup vs baseline: 3.0970x; 1.0770x over previous
//
#include <hip/hip_runtime.h>

typedef __bf16 bf16;
typedef __bf16 bf16x4 __attribute__((ext_vector_type(4)));
typedef __bf16 bf16x8 __attribute__((ext_vector_type(8)));
typedef float  f32x4  __attribute__((ext_vector_type(4)));

#define DM   1024
#define NH   16
#define DKH  64
#define DFF  4096
#define SEQL 2048
#define NTOK 8192

typedef __attribute__((address_space(1))) void GAS;
typedef __attribute__((address_space(3))) void LAS;

__device__ inline void gload_lds16(const void* g, void* l) {
    __builtin_amdgcn_global_load_lds((GAS*)g, (LAS*)l, 16, 0, 0);
}

// bare v_exp_f32 (exp2) — avoids libm exp2f's range-check sequence
__device__ inline float fast_exp2(float x) {
    float r;
    asm("v_exp_f32 %0, %1" : "=v"(r) : "v"(x));
    return r;
}

// ---------------- cast f32 -> bf16 ----------------
__global__ void cast_f32_bf16(const float* __restrict__ in, bf16* __restrict__ out, long n) {
    long i = ((long)blockIdx.x * 256 + threadIdx.x) * 4;
    long stride = (long)gridDim.x * 256 * 4;
    for (; i < n; i += stride) {
        float4 v = *(const float4*)(in + i);
        bf16x4 o = {(bf16)v.x, (bf16)v.y, (bf16)v.z, (bf16)v.w};
        *(bf16x4*)(out + i) = o;
    }
}

// ---------------- transpose + cast: src[R][C] f32 -> dst[C][R] bf16 ----------------
__global__ void transpose_cast(const float* __restrict__ src, bf16* __restrict__ dst, int R, int C) {
    __shared__ float t[32][33];
    int c0 = blockIdx.x * 32, r0 = blockIdx.y * 32;
    int tx = threadIdx.x, ty = threadIdx.y; // block (32,8)
#pragma unroll
    for (int i = 0; i < 4; ++i)
        t[ty + i * 8][tx] = src[(long)(r0 + ty + i * 8) * C + c0 + tx];
    __syncthreads();
#pragma unroll
    for (int i = 0; i < 4; ++i)
        dst[(long)(c0 + ty + i * 8) * R + r0 + tx] = (bf16)t[tx][ty + i * 8];
}

// ---------------- concat 3 bias vectors (1024 each) ----------------
__global__ void concat3(const float* __restrict__ a, const float* __restrict__ b,
                        const float* __restrict__ c, float* __restrict__ out) {
    int i = blockIdx.x * 256 + threadIdx.x;
    if (i < 1024) out[i] = a[i];
    else if (i < 2048) out[i] = b[i - 1024];
    else if (i < 3072) out[i] = c[i - 2048];
}

// ---------------- build V^T: vt[(b*16+h)*64 + d][s] ----------------
__global__ void build_vt(const bf16* __restrict__ qkv, bf16* __restrict__ vt) {
    __shared__ bf16 t[32][33];
    int bh = blockIdx.z, b = bh >> 4, h = bh & 15;
    int s0 = blockIdx.x * 32, d0 = blockIdx.y * 32;
    int tx = threadIdx.x, ty = threadIdx.y;
#pragma unroll
    for (int i = 0; i < 4; ++i)
        t[ty + i * 8][tx] = qkv[(long)(b * SEQL + s0 + ty + i * 8) * 3072 + 2 * DM + h * DKH + d0 + tx];
    __syncthreads();
#pragma unroll
    for (int i = 0; i < 4; ++i)
        vt[((long)bh * DKH + d0 + ty + i * 8) * SEQL + s0 + tx] = (bf16)t[tx][ty + i * 8];
}

// ---------------- GEMM: 4-phase fine interleave + COUNTED vmcnt (m218-V0 cell) ----------------
// 256xBN tile, BK=64, 8 waves (2Mx4N, wave=128x(BN/4)), 2 LDS buffers (128KB).
// Per tile: 4 phases {ds_read subtile; stage 1 K-half of T+1; barrier;
// lgkmcnt(0)+sched_barrier; setprio(1) 16*NR/4 MFMA setprio(0); [vmcnt]; barrier}.
// Stage order per tile: Ak0(ph0), Bk0(ph1), Ak1(ph2), Bk1(ph3). Waits: vmcnt(4)
// before ph1-end barrier (guarantees this tile's Ak1,Bk1 = oldest 4 of 8) and
// before ph3-end barrier (guarantees next tile's Ak0,Bk0). Never drains except
// the tail tile's ph1 (vmcnt(0): only 4 outstanding there, vmcnt(4) would no-op).
// Race-free: stage(T+1)->buf[(T+1)&1]; last reader (T-1) finished before its
// final barrier, which precedes T's ph0 stage.
// K-half staging is contiguous in the kg-major cell layout (cells kg*R+row,
// kg 0-3 / 4-7) -> linear gload_lds dests; fragment reads = proven 0-conflict
// pattern. BN=192: j=1 duplicates trailing cells (benign) -> loads/half = 2
// for both BN, so vmcnt constants hold for both instantiations.
// Split-K via blockIdx.z; bias applied only by z==0 (partials summed in add_ln).
template<int BN>
__global__ __launch_bounds__(512, 2)
void gemm4ph(const bf16* __restrict__ A, const bf16* __restrict__ Bt,
             const float* __restrict__ bias,
             float* __restrict__ Cf, bf16* __restrict__ Ch,
             int N, int lda, int Klen, int relu, long strideCf) {
    constexpr int NR = BN / 64;            // 256->4, 192->3
    constexpr int WCOL = BN / 4;           // per-wave N extent
    __shared__ bf16 As[2][8][256][8];      // [buf][kg=k/8][row][8], BK=64
    __shared__ bf16 Bs[2][8][BN][8];
    const int tid = threadIdx.x;
    const int lane = tid & 63;
    const int wv = tid >> 6;
    const int wr = wv >> 2, wc = wv & 3;   // 2 x 4 wave grid
    const int lr = lane & 15, lg = lane >> 4;

    unsigned gx = gridDim.x, gy = gridDim.y;
    unsigned nwg = gx * gy * gridDim.z;
    unsigned wg = (blockIdx.z * gy + blockIdx.y) * gx + blockIdx.x;
    unsigned swz = (wg & 7) * (nwg >> 3) + (wg >> 3);
    unsigned bxi = swz % gx;
    unsigned rem2 = swz / gx;
    unsigned byi = rem2 % gy, bzi = rem2 / gy;

    const long brow = (long)byi * 256;
    const long bcol = (long)bxi * BN;
    const bf16* Ap = A + (long)bzi * Klen;
    const bf16* Bp = Bt + (long)bzi * Klen;
    float* Cfp = Cf ? Cf + (long)bzi * strideCf : nullptr;
    const float* biasp = (bzi == 0) ? bias : nullptr;

    // stage one K-half (kg 4h..4h+3) of tile X: 2 loads/thread, linear LDS dest
    auto stageA = [&](int X, int h) {
        const int kt = X * 64, buf = X & 1;
#pragma unroll
        for (int j = 0; j < 2; ++j) {
            int l = j * 512 + tid;             // cell within half: 0..1023
            int kg = (l >> 8) + h * 4;
            int row = l & 255;
            gload_lds16(Ap + (brow + row) * (long)lda + kt + kg * 8, &As[buf][kg][row][0]);
        }
    };
    auto stageB = [&](int X, int h) {
        const int kt = X * 64, buf = X & 1;
        {
            int l = tid;                       // cells 0..511 of half
            int kg = l / BN + h * 4, row = l % BN;
            gload_lds16(Bp + (bcol + row) * (long)lda + kt + kg * 8, &Bs[buf][kg][row][0]);
        }
        {
            int l = 512 + (BN == 256 ? tid : (tid & 255));  // cells 512..(BN*4-1)
            int kg = l / BN + h * 4, row = l % BN;
            gload_lds16(Bp + (bcol + row) * (long)lda + kt + kg * 8, &Bs[buf][kg][row][0]);
        }
    };

    const int NT = Klen / 64;
    f32x4 acc[8][NR] = {};

    // prologue: tile 0 fully staged (8 loads); Ak0,Bk0 landed before ph0 reads
    stageA(0, 0); stageB(0, 0); stageA(0, 1); stageB(0, 1);
    asm volatile("s_waitcnt vmcnt(4)" ::: "memory");
    __builtin_amdgcn_s_barrier();
    asm volatile("" ::: "memory");

    for (int T = 0; T < NT; ++T) {
        const int cur = T & 1;
        const bool pf = (T + 1 < NT);
        bf16x8 bv0[NR], bv1[NR], af[4];
        // ---------- ph0: B[kh0] + A[kh0,m0-3] reads; stage A(T+1,k0) ----------
#pragma unroll
        for (int n = 0; n < NR; ++n)
            bv0[n] = *(const bf16x8*)(&Bs[cur][lg][wc * WCOL + n * 16 + lr][0]);
#pragma unroll
        for (int m = 0; m < 4; ++m)
            af[m] = *(const bf16x8*)(&As[cur][lg][wr * 128 + m * 16 + lr][0]);
        if (pf) stageA(T + 1, 0);
        __builtin_amdgcn_s_barrier();
        asm volatile("s_waitcnt lgkmcnt(0)" ::: "memory");
        __builtin_amdgcn_sched_barrier(0);
        __builtin_amdgcn_s_setprio(1);
#pragma unroll
        for (int m = 0; m < 4; ++m)
#pragma unroll
            for (int n = 0; n < NR; ++n)
                acc[m][n] = __builtin_amdgcn_mfma_f32_16x16x32_bf16(af[m], bv0[n], acc[m][n], 0, 0, 0);
        __builtin_amdgcn_s_setprio(0);
        asm volatile("" ::: "memory");
        __builtin_amdgcn_s_barrier();
        // ---------- ph1: A[kh0,m4-7] reads; stage B(T+1,k0); wait kh1 halves ----------
#pragma unroll
        for (int m = 0; m < 4; ++m)
            af[m] = *(const bf16x8*)(&As[cur][lg][wr * 128 + (4 + m) * 16 + lr][0]);
        if (pf) stageB(T + 1, 0);
        __builtin_amdgcn_s_barrier();
        asm volatile("s_waitcnt lgkmcnt(0)" ::: "memory");
        __builtin_amdgcn_sched_barrier(0);
        __builtin_amdgcn_s_setprio(1);
#pragma unroll
        for (int m = 0; m < 4; ++m)
#pragma unroll
            for (int n = 0; n < NR; ++n)
                acc[4 + m][n] = __builtin_amdgcn_mfma_f32_16x16x32_bf16(af[m], bv0[n], acc[4 + m][n], 0, 0, 0);
        __builtin_amdgcn_s_setprio(0);
        // this tile's Ak1,Bk1 are the oldest outstanding (4 of 8) -> counted wait
        if (pf) asm volatile("s_waitcnt vmcnt(4)" ::: "memory");
        else    asm volatile("s_waitcnt vmcnt(0)" ::: "memory");
        asm volatile("" ::: "memory");
        __builtin_amdgcn_s_barrier();
        // ---------- ph2: B[kh1] + A[kh1,m0-3] reads; stage A(T+1,k1) ----------
#pragma unroll
        for (int n = 0; n < NR; ++n)
            bv1[n] = *(const bf16x8*)(&Bs[cur][4 + lg][wc * WCOL + n * 16 + lr][0]);
#pragma unroll
        for (int m = 0; m < 4; ++m)
            af[m] = *(const bf16x8*)(&As[cur][4 + lg][wr * 128 + m * 16 + lr][0]);
        if (pf) stageA(T + 1, 1);
        __builtin_amdgcn_s_barrier();
        asm volatile("s_waitcnt lgkmcnt(0)" ::: "memory");
        __builtin_amdgcn_sched_barrier(0);
        __builtin_amdgcn_s_setprio(1);
#pragma unroll
        for (int m = 0; m < 4; ++m)
#pragma unroll
            for (int n = 0; n < NR; ++n)
                acc[m][n] = __builtin_amdgcn_mfma_f32_16x16x32_bf16(af[m], bv1[n], acc[m][n], 0, 0, 0);
        __builtin_amdgcn_s_setprio(0);
        asm volatile("" ::: "memory");
        __builtin_amdgcn_s_barrier();
        // ---------- ph3: A[kh1,m4-7] reads; stage B(T+1,k1); wait next tile's k0 ----------
#pragma unroll
        for (int m = 0; m < 4; ++m)
            af[m] = *(const bf16x8*)(&As[cur][4 + lg][wr * 128 + (4 + m) * 16 + lr][0]);
        if (pf) stageB(T + 1, 1);
        __builtin_amdgcn_s_barrier();
        asm volatile("s_waitcnt lgkmcnt(0)" ::: "memory");
        __builtin_amdgcn_sched_barrier(0);
        __builtin_amdgcn_s_setprio(1);
#pragma unroll
        for (int m = 0; m < 4; ++m)
#pragma unroll
            for (int n = 0; n < NR; ++n)
                acc[4 + m][n] = __builtin_amdgcn_mfma_f32_16x16x32_bf16(af[m], bv1[n], acc[4 + m][n], 0, 0, 0);
        __builtin_amdgcn_s_setprio(0);
        // next tile's Ak0,Bk0 are the oldest outstanding (4 of 8) -> counted wait
        if (pf) asm volatile("s_waitcnt vmcnt(4)" ::: "memory");
        asm volatile("" ::: "memory");
        __builtin_amdgcn_s_barrier();
    }

#pragma unroll
    for (int m = 0; m < 8; ++m) {
#pragma unroll
        for (int n = 0; n < NR; ++n) {
            long gcol = bcol + wc * WCOL + n * 16 + lr;
            float bv = biasp ? biasp[gcol] : 0.f;
#pragma unroll
            for (int r = 0; r < 4; ++r) {
                long grow = brow + wr * 128 + m * 16 + lg * 4 + r;
                float v = acc[m][n][r] + bv;
                if (relu) v = v > 0.f ? v : 0.f;
                if (Cfp) Cfp[grow * N + gcol] = v;
                if (Ch) Ch[grow * N + gcol] = (bf16)v;
            }
        }
    }
}

// ---------------- flash attention (r11/r12 best: defer-max, max3 tree, exp2-asm) ----------------
__global__ __launch_bounds__(256, 3)
void attn_fwd(const bf16* __restrict__ qkv, const bf16* __restrict__ vt,
              bf16* __restrict__ attn_o) {
    __shared__ bf16 Ks[2][64][64];   // [buf][kv][d], swizzled
    __shared__ bf16 Vs[2][64][64];   // [buf][d][kv], swizzled
    __shared__ bf16 Plds[4][16][64]; // per-wave P tile [q][kv], swizzled
    const int tid = threadIdx.x, lane = tid & 63, w = tid >> 6;
    const int lr = lane & 15, lg = lane >> 4;

    unsigned nwg = gridDim.x * gridDim.y;       // 1024
    unsigned wg = blockIdx.y * gridDim.x + blockIdx.x;
    unsigned cpx = nwg >> 3;
    unsigned swzid = (wg & 7) * cpx + (wg >> 3);
    const int bx = swzid % gridDim.x, bh = swzid / gridDim.x;
    const int b = bh >> 4, h = bh & 15;
    const int q0 = bx * 128 + w * 32;

    const bf16* Q  = qkv + (long)b * SEQL * 3072 + h * DKH;
    const bf16* Kp = qkv + (long)b * SEQL * 3072 + DM + h * DKH;
    const bf16* Vp = vt + (long)bh * DKH * SEQL;

    const int r0 = w * 8 + (lane >> 3);
    const int cbb = ((lane & 7) * 16) ^ ((r0 & 7) << 4);
    const int cb = cbb >> 1;

    auto stage = [&](int buf, int j0) {
#pragma unroll
        for (int c = 0; c < 2; ++c) {
            bf16* kd = &Ks[buf][0][0] + c * 2048 + w * 512 + lane * 8;
            bf16* vd = &Vs[buf][0][0] + c * 2048 + w * 512 + lane * 8;
            gload_lds16(Kp + (long)(j0 + c * 32 + r0) * 3072 + cb, kd);
            gload_lds16(Vp + (long)(c * 32 + r0) * SEQL + j0 + cb, vd);
        }
    };

    stage(0, 0);

    // Q pre-scale: (1/sqrt(64)) * log2(e) -> scores land in log2 domain
    const float QSC = 0.125f * 1.44269504f;
    bf16x8 aq[2][2];
#pragma unroll
    for (int a = 0; a < 2; ++a)
#pragma unroll
        for (int kh = 0; kh < 2; ++kh) {
            bf16x8 q = *(const bf16x8*)(Q + (long)(q0 + a * 16 + lr) * 3072 + kh * 32 + lg * 8);
#pragma unroll
            for (int e = 0; e < 8; ++e) q[e] = (bf16)((float)q[e] * QSC);
            aq[a][kh] = q;
        }

    float mrow[2] = {-1e30f, -1e30f};
    float lrow[2] = {0.f, 0.f};
    f32x4 accO[2][4] = {};
    char* pbase = (char*)&Plds[w][0][0];
    const int psw = (lr & 7) << 4;
    const f32x4 zero = {0.f, 0.f, 0.f, 0.f};
    int cur = 0;

    for (int it = 0; it < SEQL / 64; ++it) {
        if (it < SEQL / 64 - 1) {
            stage(cur ^ 1, (it + 1) * 64);
            asm volatile("s_waitcnt vmcnt(4)" ::: "memory");
        } else {
            asm volatile("s_waitcnt vmcnt(0)" ::: "memory");
        }
        __builtin_amdgcn_s_barrier();
        asm volatile("" ::: "memory");

        const char* Kbuf = (const char*)&Ks[cur][0][0];
        const char* Vbuf = (const char*)&Vs[cur][0][0];

        bf16x8 kf[4][2];
#pragma unroll
        for (int jh = 0; jh < 4; ++jh) {
            int row = jh * 16 + lr;
            int sw = (row & 7) << 4;
            kf[jh][0] = *(const bf16x8*)(Kbuf + row * 128 + ((lg * 16) ^ sw));
            kf[jh][1] = *(const bf16x8*)(Kbuf + row * 128 + ((64 + lg * 16) ^ sw));
        }
        bf16x8 vf[4][2];
#pragma unroll
        for (int c = 0; c < 4; ++c) {
            int row = c * 16 + lr;
            int sw = (row & 7) << 4;
            vf[c][0] = *(const bf16x8*)(Vbuf + row * 128 + ((lg * 16) ^ sw));
            vf[c][1] = *(const bf16x8*)(Vbuf + row * 128 + ((64 + lg * 16) ^ sw));
        }

#pragma unroll
        for (int a = 0; a < 2; ++a) {
            f32x4 s[4];
#pragma unroll
            for (int jh = 0; jh < 4; ++jh) {
                f32x4 t = __builtin_amdgcn_mfma_f32_16x16x32_bf16(kf[jh][0], aq[a][0], zero, 0, 0, 0);
                s[jh] = __builtin_amdgcn_mfma_f32_16x16x32_bf16(kf[jh][1], aq[a][1], t, 0, 0, 0);
            }
            // max over 16 lane-local values as a max3-friendly tree (v_max3_f32)
            float m0 = fmaxf(fmaxf(s[0][0], s[0][1]), fmaxf(s[0][2], s[0][3]));
            float m1 = fmaxf(fmaxf(s[1][0], s[1][1]), fmaxf(s[1][2], s[1][3]));
            float m2 = fmaxf(fmaxf(s[2][0], s[2][1]), fmaxf(s[2][2], s[2][3]));
            float m3 = fmaxf(fmaxf(s[3][0], s[3][1]), fmaxf(s[3][2], s[3][3]));
            float pm = fmaxf(fmaxf(m0, m1), fmaxf(m2, m3));
            pm = fmaxf(pm, __shfl_xor(pm, 16));
            pm = fmaxf(pm, __shfl_xor(pm, 32));
            // T13 defer-max: if max growth <= 8 (log2 domain, factor 256), keep
            // old mrow -> skip al exp, alr broadcast, and accO rescale entirely.
            int skip = __all(pm - mrow[a] <= 8.0f);
            if (!skip) {
                float mnew = fmaxf(mrow[a], pm);
                float al = fast_exp2(mrow[a] - mnew);
                mrow[a] = mnew;
                lrow[a] *= al;
                float alr[4];
#pragma unroll
                for (int r = 0; r < 4; ++r)
                    alr[r] = __shfl(al, (lane & 48) | (lg * 4 + r));
#pragma unroll
                for (int c = 0; c < 4; ++c)
#pragma unroll
                    for (int r = 0; r < 4; ++r) accO[a][c][r] *= alr[r];
            }
            float mcur = mrow[a];
            float psum = 0.f;
#pragma unroll
            for (int jh = 0; jh < 4; ++jh)
#pragma unroll
                for (int r = 0; r < 4; ++r) {
                    float p = fast_exp2(s[jh][r] - mcur);
                    s[jh][r] = p;
                    psum += p;
                }
            psum += __shfl_xor(psum, 16);
            psum += __shfl_xor(psum, 32);
            lrow[a] += psum;
#pragma unroll
            for (int jh = 0; jh < 4; ++jh) {
                bf16x4 pw = {(bf16)s[jh][0], (bf16)s[jh][1], (bf16)s[jh][2], (bf16)s[jh][3]};
                *(bf16x4*)(pbase + lr * 128 + ((jh * 32 + lg * 8) ^ psw)) = pw;
            }
            bf16x8 pa[2];
#pragma unroll
            for (int i = 0; i < 2; ++i)
                pa[i] = *(const bf16x8*)(pbase + lr * 128 + ((i * 64 + lg * 16) ^ psw));
#pragma unroll
            for (int c = 0; c < 4; ++c) {
                accO[a][c] = __builtin_amdgcn_mfma_f32_16x16x32_bf16(pa[0], vf[c][0], accO[a][c], 0, 0, 0);
                accO[a][c] = __builtin_amdgcn_mfma_f32_16x16x32_bf16(pa[1], vf[c][1], accO[a][c], 0, 0, 0);
            }
        }
        asm volatile("" ::: "memory");
        __builtin_amdgcn_s_barrier();
        cur ^= 1;
    }

#pragma unroll
    for (int a = 0; a < 2; ++a) {
        float linv = 1.0f / lrow[a];
        float invr[4];
#pragma unroll
        for (int r = 0; r < 4; ++r)
            invr[r] = __shfl(linv, (lane & 48) | (lg * 4 + r));
#pragma unroll
        for (int r = 0; r < 4; ++r) {
            long grow = (long)b * SEQL + q0 + a * 16 + lg * 4 + r;
#pragma unroll
            for (int c = 0; c < 4; ++c)
                attn_o[grow * DM + h * DKH + c * 16 + lr] = (bf16)(accO[a][c][r] * invr[r]);
        }
    }
}

// ---------------- fused residual add (+ optional 3rd input) + LayerNorm ----------------
__global__ __launch_bounds__(256)
void add_ln(const float* __restrict__ A, const float* __restrict__ B,
            const float* __restrict__ B2,
            const float* __restrict__ g, const float* __restrict__ be,
            float* __restrict__ outf, bf16* __restrict__ outh) {
    const int w = threadIdx.x >> 6, lane = threadIdx.x & 63;
    const long row = (long)blockIdx.x * 4 + w;
    const float4* pa = (const float4*)(A + row * DM);
    const float4* pb = (const float4*)(B + row * DM);
    const float4* pb2 = B2 ? (const float4*)(B2 + row * DM) : nullptr;
    float4 v[4];
    float s = 0.f;
#pragma unroll
    for (int i = 0; i < 4; ++i) {
        float4 a = pa[i * 64 + lane], bb = pb[i * 64 + lane];
        v[i] = make_float4(a.x + bb.x, a.y + bb.y, a.z + bb.z, a.w + bb.w);
        if (pb2) {
            float4 b2 = pb2[i * 64 + lane];
            v[i].x += b2.x; v[i].y += b2.y; v[i].z += b2.z; v[i].w += b2.w;
        }
        s += v[i].x + v[i].y + v[i].z + v[i].w;
    }
#pragma unroll
    for (int off = 32; off; off >>= 1) s += __shfl_xor(s, off);
    float mu = s * (1.0f / 1024.0f);
    float var = 0.f;
#pragma unroll
    for (int i = 0; i < 4; ++i) {
        float dx = v[i].x - mu, dy = v[i].y - mu, dz = v[i].z - mu, dw = v[i].w - mu;
        var += dx * dx + dy * dy + dz * dz + dw * dw;
    }
#pragma unroll
    for (int off = 32; off; off >>= 1) var += __shfl_xor(var, off);
    float rs = 1.0f / sqrtf(var * (1.0f / 1024.0f) + 1e-5f);
    const float4* pg = (const float4*)g;
    const float4* pe = (const float4*)be;
#pragma unroll
    for (int i = 0; i < 4; ++i) {
        float4 gg = pg[i * 64 + lane], ee = pe[i * 64 + lane];
        float4 o = make_float4((v[i].x - mu) * rs * gg.x + ee.x,
                               (v[i].y - mu) * rs * gg.y + ee.y,
                               (v[i].z - mu) * rs * gg.z + ee.z,
                               (v[i].w - mu) * rs * gg.w + ee.w);
        if (outf) ((float4*)(outf + row * DM))[i * 64 + lane] = o;
        if (outh) {
            bf16x4 ho = {(bf16)o.x, (bf16)o.y, (bf16)o.z, (bf16)o.w};
            *(bf16x4*)(outh + row * DM + (i * 64 + lane) * 4) = ho;
        }
    }
}

extern "C" void kernel_launch(void* const* d_in, const int* in_sizes, int n_in,
                              void* d_out, int out_size, void* d_ws, size_t ws_size,
                              hipStream_t stream) {
    const float* x   = (const float*)d_in[0];
    const float* Wq  = (const float*)d_in[1];
    const float* bq  = (const float*)d_in[2];
    const float* Wk  = (const float*)d_in[3];
    const float* bk  = (const float*)d_in[4];
    const float* Wv  = (const float*)d_in[5];
    const float* bv  = (const float*)d_in[6];
    const float* Wo  = (const float*)d_in[7];
    const float* bo  = (const float*)d_in[8];
    const float* W1  = (const float*)d_in[9];
    const float* b1  = (const float*)d_in[10];
    const float* W2  = (const float*)d_in[11];
    const float* b2  = (const float*)d_in[12];
    const float* g1  = (const float*)d_in[13];
    const float* be1 = (const float*)d_in[14];
    const float* g2  = (const float*)d_in[15];
    const float* be2 = (const float*)d_in[16];
    float* out = (float*)d_out;

    char* ws = (char*)d_ws;
    size_t off = 0;
    auto alloc = [&](size_t bytes) {
        void* p = ws + off;
        off += (bytes + 255) & ~(size_t)255;
        return p;
    };
    bf16* xh    = (bf16*)alloc((size_t)NTOK * DM * 2);
    bf16* wqkvt = (bf16*)alloc((size_t)3072 * 1024 * 2);
    bf16* wot   = (bf16*)alloc((size_t)1024 * 1024 * 2);
    bf16* w1t   = (bf16*)alloc((size_t)4096 * 1024 * 2);
    bf16* w2t   = (bf16*)alloc((size_t)1024 * 4096 * 2);
    float* bqkv = (float*)alloc((size_t)3072 * 4);
    bf16* qkv   = (bf16*)alloc((size_t)NTOK * 3072 * 2);
    bf16* vtb   = (bf16*)alloc((size_t)NTOK * DM * 2);
    bf16* attno = (bf16*)alloc((size_t)NTOK * DM * 2);
    float* projf  = (float*)alloc((size_t)NTOK * DM * 4);  // split-K partial 0
    float* projf1 = (float*)alloc((size_t)NTOK * DM * 4);  // split-K partial 1
    float* x1f  = (float*)alloc((size_t)NTOK * DM * 4);
    bf16* x1h   = (bf16*)alloc((size_t)NTOK * DM * 2);
    bf16* ffh   = (bf16*)qkv; // alias: qkv+vtb dead after attn; 67MB for [8192][4096]

    dim3 tb(32, 8);
    cast_f32_bf16<<<2048, 256, 0, stream>>>(x, xh, (long)NTOK * DM);
    transpose_cast<<<dim3(32, 32), tb, 0, stream>>>(Wq, wqkvt, 1024, 1024);
    transpose_cast<<<dim3(32, 32), tb, 0, stream>>>(Wk, wqkvt + (size_t)1024 * 1024, 1024, 1024);
    transpose_cast<<<dim3(32, 32), tb, 0, stream>>>(Wv, wqkvt + (size_t)2048 * 1024, 1024, 1024);
    transpose_cast<<<dim3(32, 32), tb, 0, stream>>>(Wo, wot, 1024, 1024);
    transpose_cast<<<dim3(128, 32), tb, 0, stream>>>(W1, w1t, 1024, 4096);
    transpose_cast<<<dim3(32, 128), tb, 0, stream>>>(W2, w2t, 4096, 1024);
    concat3<<<12, 256, 0, stream>>>(bq, bk, bv, bqkv);

    // QKV: [8192,1024]@[1024,3072] -> bf16 (BN=192: grid 16x32=512 = 2 even rounds)
    gemm4ph<192><<<dim3(3072 / 192, 8192 / 256, 1), 512, 0, stream>>>(
        xh, wqkvt, bqkv, nullptr, qkv, 3072, 1024, 1024, 0, 0);
    build_vt<<<dim3(SEQL / 32, 2, 64), tb, 0, stream>>>(qkv, vtb);
    attn_fwd<<<dim3(SEQL / 128, 64), 256, 0, stream>>>(qkv, vtb, attno);
    // Wo: split-K x2 (Klen=512), grid 4x32x2=256 -> projf/projf1 fp32
    gemm4ph<256><<<dim3(1024 / 256, 8192 / 256, 2), 512, 0, stream>>>(
        attno, wot, bo, projf, nullptr, 1024, 1024, 512, 0, (long)NTOK * DM);
    add_ln<<<NTOK / 4, 256, 0, stream>>>(x, projf, projf1, g1, be1, x1f, x1h);
    // FFN1: [8192,1024]@[1024,4096]+ReLU -> bf16 (grid 16x32=512)
    gemm4ph<256><<<dim3(4096 / 256, 8192 / 256, 1), 512, 0, stream>>>(
        x1h, w1t, b1, nullptr, ffh, 4096, 1024, 1024, 1, 0);
    // FFN2: split-K x2 (Klen=2048), grid 4x32x2=256 -> projf/projf1
    gemm4ph<256><<<dim3(1024 / 256, 8192 / 256, 2), 512, 0, stream>>>(
        ffh, w2t, b2, projf, nullptr, 1024, 4096, 2048, 0, (long)NTOK * DM);
    add_ln<<<NTOK / 4, 256, 0, stream>>>(x1f, projf, projf1, g2, be2, out, nullptr);
}

// Round 16
// 497.058 us; speedup vs baseline: 3.1849x; 1.0284x over previous
//
#include <hip/hip_runtime.h>

typedef __bf16 bf16;
typedef __bf16 bf16x4 __attribute__((ext_vector_type(4)));
typedef __bf16 bf16x8 __attribute__((ext_vector_type(8)));
typedef float  f32x4  __attribute__((ext_vector_type(4)));

#define DM   1024
#define NH   16
#define DKH  64
#define DFF  4096
#define SEQL 2048
#define NTOK 8192

typedef __attribute__((address_space(1))) void GAS;
typedef __attribute__((address_space(3))) void LAS;

__device__ inline void gload_lds16(const void* g, void* l) {
    __builtin_amdgcn_global_load_lds((GAS*)g, (LAS*)l, 16, 0, 0);
}

// bare v_exp_f32 (exp2) — avoids libm exp2f's range-check sequence
__device__ inline float fast_exp2(float x) {
    float r;
    asm("v_exp_f32 %0, %1" : "=v"(r) : "v"(x));
    return r;
}

// ---------------- cast f32 -> bf16 ----------------
__global__ void cast_f32_bf16(const float* __restrict__ in, bf16* __restrict__ out, long n) {
    long i = ((long)blockIdx.x * 256 + threadIdx.x) * 4;
    long stride = (long)gridDim.x * 256 * 4;
    for (; i < n; i += stride) {
        float4 v = *(const float4*)(in + i);
        bf16x4 o = {(bf16)v.x, (bf16)v.y, (bf16)v.z, (bf16)v.w};
        *(bf16x4*)(out + i) = o;
    }
}

// ---------------- transpose + cast: src[R][C] f32 -> dst[C][R] bf16 ----------------
__global__ void transpose_cast(const float* __restrict__ src, bf16* __restrict__ dst, int R, int C) {
    __shared__ float t[32][33];
    int c0 = blockIdx.x * 32, r0 = blockIdx.y * 32;
    int tx = threadIdx.x, ty = threadIdx.y; // block (32,8)
#pragma unroll
    for (int i = 0; i < 4; ++i)
        t[ty + i * 8][tx] = src[(long)(r0 + ty + i * 8) * C + c0 + tx];
    __syncthreads();
#pragma unroll
    for (int i = 0; i < 4; ++i)
        dst[(long)(c0 + ty + i * 8) * R + r0 + tx] = (bf16)t[tx][ty + i * 8];
}

// ---------------- concat 3 bias vectors (1024 each) ----------------
__global__ void concat3(const float* __restrict__ a, const float* __restrict__ b,
                        const float* __restrict__ c, float* __restrict__ out) {
    int i = blockIdx.x * 256 + threadIdx.x;
    if (i < 1024) out[i] = a[i];
    else if (i < 2048) out[i] = b[i - 1024];
    else if (i < 3072) out[i] = c[i - 2048];
}

// ---------------- build V^T: vt[(b*16+h)*64 + d][s] ----------------
__global__ void build_vt(const bf16* __restrict__ qkv, bf16* __restrict__ vt) {
    __shared__ bf16 t[32][33];
    int bh = blockIdx.z, b = bh >> 4, h = bh & 15;
    int s0 = blockIdx.x * 32, d0 = blockIdx.y * 32;
    int tx = threadIdx.x, ty = threadIdx.y;
#pragma unroll
    for (int i = 0; i < 4; ++i)
        t[ty + i * 8][tx] = qkv[(long)(b * SEQL + s0 + ty + i * 8) * 3072 + 2 * DM + h * DKH + d0 + tx];
    __syncthreads();
#pragma unroll
    for (int i = 0; i < 4; ++i)
        vt[((long)bh * DKH + d0 + ty + i * 8) * SEQL + s0 + tx] = (bf16)t[tx][ty + i * 8];
}

// ---------------- GEMM: 4-phase fine interleave + COUNTED vmcnt (r15 best, verbatim) ----------------
template<int BN>
__global__ __launch_bounds__(512, 2)
void gemm4ph(const bf16* __restrict__ A, const bf16* __restrict__ Bt,
             const float* __restrict__ bias,
             float* __restrict__ Cf, bf16* __restrict__ Ch,
             int N, int lda, int Klen, int relu, long strideCf) {
    constexpr int NR = BN / 64;            // 256->4, 192->3
    constexpr int WCOL = BN / 4;           // per-wave N extent
    __shared__ bf16 As[2][8][256][8];      // [buf][kg=k/8][row][8], BK=64
    __shared__ bf16 Bs[2][8][BN][8];
    const int tid = threadIdx.x;
    const int lane = tid & 63;
    const int wv = tid >> 6;
    const int wr = wv >> 2, wc = wv & 3;   // 2 x 4 wave grid
    const int lr = lane & 15, lg = lane >> 4;

    unsigned gx = gridDim.x, gy = gridDim.y;
    unsigned nwg = gx * gy * gridDim.z;
    unsigned wg = (blockIdx.z * gy + blockIdx.y) * gx + blockIdx.x;
    unsigned swz = (wg & 7) * (nwg >> 3) + (wg >> 3);
    unsigned bxi = swz % gx;
    unsigned rem2 = swz / gx;
    unsigned byi = rem2 % gy, bzi = rem2 / gy;

    const long brow = (long)byi * 256;
    const long bcol = (long)bxi * BN;
    const bf16* Ap = A + (long)bzi * Klen;
    const bf16* Bp = Bt + (long)bzi * Klen;
    float* Cfp = Cf ? Cf + (long)bzi * strideCf : nullptr;
    const float* biasp = (bzi == 0) ? bias : nullptr;

    auto stageA = [&](int X, int h) {
        const int kt = X * 64, buf = X & 1;
#pragma unroll
        for (int j = 0; j < 2; ++j) {
            int l = j * 512 + tid;             // cell within half: 0..1023
            int kg = (l >> 8) + h * 4;
            int row = l & 255;
            gload_lds16(Ap + (brow + row) * (long)lda + kt + kg * 8, &As[buf][kg][row][0]);
        }
    };
    auto stageB = [&](int X, int h) {
        const int kt = X * 64, buf = X & 1;
        {
            int l = tid;                       // cells 0..511 of half
            int kg = l / BN + h * 4, row = l % BN;
            gload_lds16(Bp + (bcol + row) * (long)lda + kt + kg * 8, &Bs[buf][kg][row][0]);
        }
        {
            int l = 512 + (BN == 256 ? tid : (tid & 255));  // cells 512..(BN*4-1)
            int kg = l / BN + h * 4, row = l % BN;
            gload_lds16(Bp + (bcol + row) * (long)lda + kt + kg * 8, &Bs[buf][kg][row][0]);
        }
    };

    const int NT = Klen / 64;
    f32x4 acc[8][NR] = {};

    stageA(0, 0); stageB(0, 0); stageA(0, 1); stageB(0, 1);
    asm volatile("s_waitcnt vmcnt(4)" ::: "memory");
    __builtin_amdgcn_s_barrier();
    asm volatile("" ::: "memory");

    for (int T = 0; T < NT; ++T) {
        const int cur = T & 1;
        const bool pf = (T + 1 < NT);
        bf16x8 bv0[NR], bv1[NR], af[4];
        // ---------- ph0 ----------
#pragma unroll
        for (int n = 0; n < NR; ++n)
            bv0[n] = *(const bf16x8*)(&Bs[cur][lg][wc * WCOL + n * 16 + lr][0]);
#pragma unroll
        for (int m = 0; m < 4; ++m)
            af[m] = *(const bf16x8*)(&As[cur][lg][wr * 128 + m * 16 + lr][0]);
        if (pf) stageA(T + 1, 0);
        __builtin_amdgcn_s_barrier();
        asm volatile("s_waitcnt lgkmcnt(0)" ::: "memory");
        __builtin_amdgcn_sched_barrier(0);
        __builtin_amdgcn_s_setprio(1);
#pragma unroll
        for (int m = 0; m < 4; ++m)
#pragma unroll
            for (int n = 0; n < NR; ++n)
                acc[m][n] = __builtin_amdgcn_mfma_f32_16x16x32_bf16(af[m], bv0[n], acc[m][n], 0, 0, 0);
        __builtin_amdgcn_s_setprio(0);
        asm volatile("" ::: "memory");
        __builtin_amdgcn_s_barrier();
        // ---------- ph1 ----------
#pragma unroll
        for (int m = 0; m < 4; ++m)
            af[m] = *(const bf16x8*)(&As[cur][lg][wr * 128 + (4 + m) * 16 + lr][0]);
        if (pf) stageB(T + 1, 0);
        __builtin_amdgcn_s_barrier();
        asm volatile("s_waitcnt lgkmcnt(0)" ::: "memory");
        __builtin_amdgcn_sched_barrier(0);
        __builtin_amdgcn_s_setprio(1);
#pragma unroll
        for (int m = 0; m < 4; ++m)
#pragma unroll
            for (int n = 0; n < NR; ++n)
                acc[4 + m][n] = __builtin_amdgcn_mfma_f32_16x16x32_bf16(af[m], bv0[n], acc[4 + m][n], 0, 0, 0);
        __builtin_amdgcn_s_setprio(0);
        if (pf) asm volatile("s_waitcnt vmcnt(4)" ::: "memory");
        else    asm volatile("s_waitcnt vmcnt(0)" ::: "memory");
        asm volatile("" ::: "memory");
        __builtin_amdgcn_s_barrier();
        // ---------- ph2 ----------
#pragma unroll
        for (int n = 0; n < NR; ++n)
            bv1[n] = *(const bf16x8*)(&Bs[cur][4 + lg][wc * WCOL + n * 16 + lr][0]);
#pragma unroll
        for (int m = 0; m < 4; ++m)
            af[m] = *(const bf16x8*)(&As[cur][4 + lg][wr * 128 + m * 16 + lr][0]);
        if (pf) stageA(T + 1, 1);
        __builtin_amdgcn_s_barrier();
        asm volatile("s_waitcnt lgkmcnt(0)" ::: "memory");
        __builtin_amdgcn_sched_barrier(0);
        __builtin_amdgcn_s_setprio(1);
#pragma unroll
        for (int m = 0; m < 4; ++m)
#pragma unroll
            for (int n = 0; n < NR; ++n)
                acc[m][n] = __builtin_amdgcn_mfma_f32_16x16x32_bf16(af[m], bv1[n], acc[m][n], 0, 0, 0);
        __builtin_amdgcn_s_setprio(0);
        asm volatile("" ::: "memory");
        __builtin_amdgcn_s_barrier();
        // ---------- ph3 ----------
#pragma unroll
        for (int m = 0; m < 4; ++m)
            af[m] = *(const bf16x8*)(&As[cur][4 + lg][wr * 128 + (4 + m) * 16 + lr][0]);
        if (pf) stageB(T + 1, 1);
        __builtin_amdgcn_s_barrier();
        asm volatile("s_waitcnt lgkmcnt(0)" ::: "memory");
        __builtin_amdgcn_sched_barrier(0);
        __builtin_amdgcn_s_setprio(1);
#pragma unroll
        for (int m = 0; m < 4; ++m)
#pragma unroll
            for (int n = 0; n < NR; ++n)
                acc[4 + m][n] = __builtin_amdgcn_mfma_f32_16x16x32_bf16(af[m], bv1[n], acc[4 + m][n], 0, 0, 0);
        __builtin_amdgcn_s_setprio(0);
        if (pf) asm volatile("s_waitcnt vmcnt(4)" ::: "memory");
        asm volatile("" ::: "memory");
        __builtin_amdgcn_s_barrier();
    }

#pragma unroll
    for (int m = 0; m < 8; ++m) {
#pragma unroll
        for (int n = 0; n < NR; ++n) {
            long gcol = bcol + wc * WCOL + n * 16 + lr;
            float bv = biasp ? biasp[gcol] : 0.f;
#pragma unroll
            for (int r = 0; r < 4; ++r) {
                long grow = brow + wr * 128 + m * 16 + lg * 4 + r;
                float v = acc[m][n][r] + bv;
                if (relu) v = v > 0.f ? v : 0.f;
                if (Cfp) Cfp[grow * N + gcol] = v;
                if (Ch) Ch[grow * N + gcol] = (bf16)v;
            }
        }
    }
}

// ---------------- flash attention: lane-partial lrow + rescale-path-only max reduce ----------------
__global__ __launch_bounds__(256, 3)
void attn_fwd(const bf16* __restrict__ qkv, const bf16* __restrict__ vt,
              bf16* __restrict__ attn_o) {
    __shared__ bf16 Ks[2][64][64];   // [buf][kv][d], swizzled
    __shared__ bf16 Vs[2][64][64];   // [buf][d][kv], swizzled
    __shared__ bf16 Plds[4][16][64]; // per-wave P tile [q][kv], swizzled
    const int tid = threadIdx.x, lane = tid & 63, w = tid >> 6;
    const int lr = lane & 15, lg = lane >> 4;

    unsigned nwg = gridDim.x * gridDim.y;       // 1024
    unsigned wg = blockIdx.y * gridDim.x + blockIdx.x;
    unsigned cpx = nwg >> 3;
    unsigned swzid = (wg & 7) * cpx + (wg >> 3);
    const int bx = swzid % gridDim.x, bh = swzid / gridDim.x;
    const int b = bh >> 4, h = bh & 15;
    const int q0 = bx * 128 + w * 32;

    const bf16* Q  = qkv + (long)b * SEQL * 3072 + h * DKH;
    const bf16* Kp = qkv + (long)b * SEQL * 3072 + DM + h * DKH;
    const bf16* Vp = vt + (long)bh * DKH * SEQL;

    const int r0 = w * 8 + (lane >> 3);
    const int cbb = ((lane & 7) * 16) ^ ((r0 & 7) << 4);
    const int cb = cbb >> 1;

    auto stage = [&](int buf, int j0) {
#pragma unroll
        for (int c = 0; c < 2; ++c) {
            bf16* kd = &Ks[buf][0][0] + c * 2048 + w * 512 + lane * 8;
            bf16* vd = &Vs[buf][0][0] + c * 2048 + w * 512 + lane * 8;
            gload_lds16(Kp + (long)(j0 + c * 32 + r0) * 3072 + cb, kd);
            gload_lds16(Vp + (long)(c * 32 + r0) * SEQL + j0 + cb, vd);
        }
    };

    stage(0, 0);

    // Q pre-scale: (1/sqrt(64)) * log2(e) -> scores land in log2 domain
    const float QSC = 0.125f * 1.44269504f;
    bf16x8 aq[2][2];
#pragma unroll
    for (int a = 0; a < 2; ++a)
#pragma unroll
        for (int kh = 0; kh < 2; ++kh) {
            bf16x8 q = *(const bf16x8*)(Q + (long)(q0 + a * 16 + lr) * 3072 + kh * 32 + lg * 8);
#pragma unroll
            for (int e = 0; e < 8; ++e) q[e] = (bf16)((float)q[e] * QSC);
            aq[a][kh] = q;
        }

    float mrow[2] = {-1e30f, -1e30f};
    float lrow[2] = {0.f, 0.f};   // LANE-PARTIAL: lane (lg,lr) holds q=lr's sum over its 16-kv slice
    f32x4 accO[2][4] = {};
    char* pbase = (char*)&Plds[w][0][0];
    const int psw = (lr & 7) << 4;
    const f32x4 zero = {0.f, 0.f, 0.f, 0.f};
    int cur = 0;

    for (int it = 0; it < SEQL / 64; ++it) {
        if (it < SEQL / 64 - 1) {
            stage(cur ^ 1, (it + 1) * 64);
            asm volatile("s_waitcnt vmcnt(4)" ::: "memory");
        } else {
            asm volatile("s_waitcnt vmcnt(0)" ::: "memory");
        }
        __builtin_amdgcn_s_barrier();
        asm volatile("" ::: "memory");

        const char* Kbuf = (const char*)&Ks[cur][0][0];
        const char* Vbuf = (const char*)&Vs[cur][0][0];

        bf16x8 kf[4][2];
#pragma unroll
        for (int jh = 0; jh < 4; ++jh) {
            int row = jh * 16 + lr;
            int sw = (row & 7) << 4;
            kf[jh][0] = *(const bf16x8*)(Kbuf + row * 128 + ((lg * 16) ^ sw));
            kf[jh][1] = *(const bf16x8*)(Kbuf + row * 128 + ((64 + lg * 16) ^ sw));
        }
        bf16x8 vf[4][2];
#pragma unroll
        for (int c = 0; c < 4; ++c) {
            int row = c * 16 + lr;
            int sw = (row & 7) << 4;
            vf[c][0] = *(const bf16x8*)(Vbuf + row * 128 + ((lg * 16) ^ sw));
            vf[c][1] = *(const bf16x8*)(Vbuf + row * 128 + ((64 + lg * 16) ^ sw));
        }

#pragma unroll
        for (int a = 0; a < 2; ++a) {
            f32x4 s[4];
#pragma unroll
            for (int jh = 0; jh < 4; ++jh) {
                f32x4 t = __builtin_amdgcn_mfma_f32_16x16x32_bf16(kf[jh][0], aq[a][0], zero, 0, 0, 0);
                s[jh] = __builtin_amdgcn_mfma_f32_16x16x32_bf16(kf[jh][1], aq[a][1], t, 0, 0, 0);
            }
            // lane-local max over 16 values (max3-friendly tree)
            float m0 = fmaxf(fmaxf(s[0][0], s[0][1]), fmaxf(s[0][2], s[0][3]));
            float m1 = fmaxf(fmaxf(s[1][0], s[1][1]), fmaxf(s[1][2], s[1][3]));
            float m2 = fmaxf(fmaxf(s[2][0], s[2][1]), fmaxf(s[2][2], s[2][3]));
            float m3 = fmaxf(fmaxf(s[3][0], s[3][1]), fmaxf(s[3][2], s[3][3]));
            float pmloc = fmaxf(fmaxf(m0, m1), fmaxf(m2, m3));
            // T13 guard on LOCAL maxima: __all over the wave == global-max test.
            // Cross-lane max reduce only needed on the (rare) rescale path.
            int skip = __all(pmloc - mrow[a] <= 8.0f);
            if (!skip) {
                float pm = fmaxf(pmloc, __shfl_xor(pmloc, 16));
                pm = fmaxf(pm, __shfl_xor(pm, 32));
                float mnew = fmaxf(mrow[a], pm);
                float al = fast_exp2(mrow[a] - mnew);   // al uniform across lg for fixed lr
                mrow[a] = mnew;
                lrow[a] *= al;                           // lane-partial rescale: consistent
                float alr[4];
#pragma unroll
                for (int r = 0; r < 4; ++r)
                    alr[r] = __shfl(al, (lane & 48) | (lg * 4 + r));
#pragma unroll
                for (int c = 0; c < 4; ++c)
#pragma unroll
                    for (int r = 0; r < 4; ++r) accO[a][c][r] *= alr[r];
            }
            float mcur = mrow[a];
            float psum = 0.f;
#pragma unroll
            for (int jh = 0; jh < 4; ++jh)
#pragma unroll
                for (int r = 0; r < 4; ++r) {
                    float p = fast_exp2(s[jh][r] - mcur);
                    s[jh][r] = p;
                    psum += p;
                }
            lrow[a] += psum;   // deferred cross-lane reduce (epilogue)
#pragma unroll
            for (int jh = 0; jh < 4; ++jh) {
                bf16x4 pw = {(bf16)s[jh][0], (bf16)s[jh][1], (bf16)s[jh][2], (bf16)s[jh][3]};
                *(bf16x4*)(pbase + lr * 128 + ((jh * 32 + lg * 8) ^ psw)) = pw;
            }
            bf16x8 pa[2];
#pragma unroll
            for (int i = 0; i < 2; ++i)
                pa[i] = *(const bf16x8*)(pbase + lr * 128 + ((i * 64 + lg * 16) ^ psw));
#pragma unroll
            for (int c = 0; c < 4; ++c) {
                accO[a][c] = __builtin_amdgcn_mfma_f32_16x16x32_bf16(pa[0], vf[c][0], accO[a][c], 0, 0, 0);
                accO[a][c] = __builtin_amdgcn_mfma_f32_16x16x32_bf16(pa[1], vf[c][1], accO[a][c], 0, 0, 0);
            }
        }
        asm volatile("" ::: "memory");
        __builtin_amdgcn_s_barrier();
        cur ^= 1;
    }

#pragma unroll
    for (int a = 0; a < 2; ++a) {
        // epilogue: reduce lane-partial lrow across the 4 lg groups (once)
        float lsum = lrow[a];
        lsum += __shfl_xor(lsum, 16);
        lsum += __shfl_xor(lsum, 32);
        float linv = 1.0f / lsum;
        float invr[4];
#pragma unroll
        for (int r = 0; r < 4; ++r)
            invr[r] = __shfl(linv, (lane & 48) | (lg * 4 + r));
#pragma unroll
        for (int r = 0; r < 4; ++r) {
            long grow = (long)b * SEQL + q0 + a * 16 + lg * 4 + r;
#pragma unroll
            for (int c = 0; c < 4; ++c)
                attn_o[grow * DM + h * DKH + c * 16 + lr] = (bf16)(accO[a][c][r] * invr[r]);
        }
    }
}

// ---------------- fused residual add (+ optional 3rd input) + LayerNorm ----------------
__global__ __launch_bounds__(256)
void add_ln(const float* __restrict__ A, const float* __restrict__ B,
            const float* __restrict__ B2,
            const float* __restrict__ g, const float* __restrict__ be,
            float* __restrict__ outf, bf16* __restrict__ outh) {
    const int w = threadIdx.x >> 6, lane = threadIdx.x & 63;
    const long row = (long)blockIdx.x * 4 + w;
    const float4* pa = (const float4*)(A + row * DM);
    const float4* pb = (const float4*)(B + row * DM);
    const float4* pb2 = B2 ? (const float4*)(B2 + row * DM) : nullptr;
    float4 v[4];
    float s = 0.f;
#pragma unroll
    for (int i = 0; i < 4; ++i) {
        float4 a = pa[i * 64 + lane], bb = pb[i * 64 + lane];
        v[i] = make_float4(a.x + bb.x, a.y + bb.y, a.z + bb.z, a.w + bb.w);
        if (pb2) {
            float4 b2 = pb2[i * 64 + lane];
            v[i].x += b2.x; v[i].y += b2.y; v[i].z += b2.z; v[i].w += b2.w;
        }
        s += v[i].x + v[i].y + v[i].z + v[i].w;
    }
#pragma unroll
    for (int off = 32; off; off >>= 1) s += __shfl_xor(s, off);
    float mu = s * (1.0f / 1024.0f);
    float var = 0.f;
#pragma unroll
    for (int i = 0; i < 4; ++i) {
        float dx = v[i].x - mu, dy = v[i].y - mu, dz = v[i].z - mu, dw = v[i].w - mu;
        var += dx * dx + dy * dy + dz * dz + dw * dw;
    }
#pragma unroll
    for (int off = 32; off; off >>= 1) var += __shfl_xor(var, off);
    float rs = 1.0f / sqrtf(var * (1.0f / 1024.0f) + 1e-5f);
    const float4* pg = (const float4*)g;
    const float4* pe = (const float4*)be;
#pragma unroll
    for (int i = 0; i < 4; ++i) {
        float4 gg = pg[i * 64 + lane], ee = pe[i * 64 + lane];
        float4 o = make_float4((v[i].x - mu) * rs * gg.x + ee.x,
                               (v[i].y - mu) * rs * gg.y + ee.y,
                               (v[i].z - mu) * rs * gg.z + ee.z,
                               (v[i].w - mu) * rs * gg.w + ee.w);
        if (outf) ((float4*)(outf + row * DM))[i * 64 + lane] = o;
        if (outh) {
            bf16x4 ho = {(bf16)o.x, (bf16)o.y, (bf16)o.z, (bf16)o.w};
            *(bf16x4*)(outh + row * DM + (i * 64 + lane) * 4) = ho;
        }
    }
}

extern "C" void kernel_launch(void* const* d_in, const int* in_sizes, int n_in,
                              void* d_out, int out_size, void* d_ws, size_t ws_size,
                              hipStream_t stream) {
    const float* x   = (const float*)d_in[0];
    const float* Wq  = (const float*)d_in[1];
    const float* bq  = (const float*)d_in[2];
    const float* Wk  = (const float*)d_in[3];
    const float* bk  = (const float*)d_in[4];
    const float* Wv  = (const float*)d_in[5];
    const float* bv  = (const float*)d_in[6];
    const float* Wo  = (const float*)d_in[7];
    const float* bo  = (const float*)d_in[8];
    const float* W1  = (const float*)d_in[9];
    const float* b1  = (const float*)d_in[10];
    const float* W2  = (const float*)d_in[11];
    const float* b2  = (const float*)d_in[12];
    const float* g1  = (const float*)d_in[13];
    const float* be1 = (const float*)d_in[14];
    const float* g2  = (const float*)d_in[15];
    const float* be2 = (const float*)d_in[16];
    float* out = (float*)d_out;

    char* ws = (char*)d_ws;
    size_t off = 0;
    auto alloc = [&](size_t bytes) {
        void* p = ws + off;
        off += (bytes + 255) & ~(size_t)255;
        return p;
    };
    bf16* xh    = (bf16*)alloc((size_t)NTOK * DM * 2);
    bf16* wqkvt = (bf16*)alloc((size_t)3072 * 1024 * 2);
    bf16* wot   = (bf16*)alloc((size_t)1024 * 1024 * 2);
    bf16* w1t   = (bf16*)alloc((size_t)4096 * 1024 * 2);
    bf16* w2t   = (bf16*)alloc((size_t)1024 * 4096 * 2);
    float* bqkv = (float*)alloc((size_t)3072 * 4);
    bf16* qkv   = (bf16*)alloc((size_t)NTOK * 3072 * 2);
    bf16* vtb   = (bf16*)alloc((size_t)NTOK * DM * 2);
    bf16* attno = (bf16*)alloc((size_t)NTOK * DM * 2);
    float* projf  = (float*)alloc((size_t)NTOK * DM * 4);  // split-K partial 0
    float* projf1 = (float*)alloc((size_t)NTOK * DM * 4);  // split-K partial 1
    float* x1f  = (float*)alloc((size_t)NTOK * DM * 4);
    bf16* x1h   = (bf16*)alloc((size_t)NTOK * DM * 2);
    bf16* ffh   = (bf16*)qkv; // alias: qkv+vtb dead after attn; 67MB for [8192][4096]

    dim3 tb(32, 8);
    cast_f32_bf16<<<2048, 256, 0, stream>>>(x, xh, (long)NTOK * DM);
    transpose_cast<<<dim3(32, 32), tb, 0, stream>>>(Wq, wqkvt, 1024, 1024);
    transpose_cast<<<dim3(32, 32), tb, 0, stream>>>(Wk, wqkvt + (size_t)1024 * 1024, 1024, 1024);
    transpose_cast<<<dim3(32, 32), tb, 0, stream>>>(Wv, wqkvt + (size_t)2048 * 1024, 1024, 1024);
    transpose_cast<<<dim3(32, 32), tb, 0, stream>>>(Wo, wot, 1024, 1024);
    transpose_cast<<<dim3(128, 32), tb, 0, stream>>>(W1, w1t, 1024, 4096);
    transpose_cast<<<dim3(32, 128), tb, 0, stream>>>(W2, w2t, 4096, 1024);
    concat3<<<12, 256, 0, stream>>>(bq, bk, bv, bqkv);

    // QKV: [8192,1024]@[1024,3072] -> bf16 (BN=192: grid 16x32=512 = 2 even rounds)
    gemm4ph<192><<<dim3(3072 / 192, 8192 / 256, 1), 512, 0, stream>>>(
        xh, wqkvt, bqkv, nullptr, qkv, 3072, 1024, 1024, 0, 0);
    build_vt<<<dim3(SEQL / 32, 2, 64), tb, 0, stream>>>(qkv, vtb);
    attn_fwd<<<dim3(SEQL / 128, 64), 256, 0, stream>>>(qkv, vtb, attno);
    // Wo: split-K x2 (Klen=512), grid 4x32x2=256 -> projf/projf1 fp32
    gemm4ph<256><<<dim3(1024 / 256, 8192 / 256, 2), 512, 0, stream>>>(
        attno, wot, bo, projf, nullptr, 1024, 1024, 512, 0, (long)NTOK * DM);
    add_ln<<<NTOK / 4, 256, 0, stream>>>(x, projf, projf1, g1, be1, x1f, x1h);
    // FFN1: [8192,1024]@[1024,4096]+ReLU -> bf16 (grid 16x32=512)
    gemm4ph<256><<<dim3(4096 / 256, 8192 / 256, 1), 512, 0, stream>>>(
        x1h, w1t, b1, nullptr, ffh, 4096, 1024, 1024, 1, 0);
    // FFN2: split-K x2 (Klen=2048), grid 4x32x2=256 -> projf/projf1
    gemm4ph<256><<<dim3(1024 / 256, 8192 / 256, 2), 512, 0, stream>>>(
        ffh, w2t, b2, projf, nullptr, 1024, 4096, 2048, 0, (long)NTOK * DM);
    add_ln<<<NTOK / 4, 256, 0, stream>>>(x1f, projf, projf1, g2, be2, out, nullptr);
}

// Round 17
// 463.092 us; speedup vs baseline: 3.4185x; 1.0733x over previous
//
#include <hip/hip_runtime.h>

typedef __bf16 bf16;
typedef __bf16 bf16x4 __attribute__((ext_vector_type(4)));
typedef __bf16 bf16x8 __attribute__((ext_vector_type(8)));
typedef float  f32x4  __attribute__((ext_vector_type(4)));

#define DM   1024
#define NH   16
#define DKH  64
#define DFF  4096
#define SEQL 2048
#define NTOK 8192

typedef __attribute__((address_space(1))) void GAS;
typedef __attribute__((address_space(3))) void LAS;

__device__ inline void gload_lds16(const void* g, void* l) {
    __builtin_amdgcn_global_load_lds((GAS*)g, (LAS*)l, 16, 0, 0);
}

// bare v_exp_f32 (exp2) — avoids libm exp2f's range-check sequence
__device__ inline float fast_exp2(float x) {
    float r;
    asm("v_exp_f32 %0, %1" : "=v"(r) : "v"(x));
    return r;
}

// ---------------- cast f32 -> bf16 ----------------
__global__ void cast_f32_bf16(const float* __restrict__ in, bf16* __restrict__ out, long n) {
    long i = ((long)blockIdx.x * 256 + threadIdx.x) * 4;
    long stride = (long)gridDim.x * 256 * 4;
    for (; i < n; i += stride) {
        float4 v = *(const float4*)(in + i);
        bf16x4 o = {(bf16)v.x, (bf16)v.y, (bf16)v.z, (bf16)v.w};
        *(bf16x4*)(out + i) = o;
    }
}

// ---------------- transpose + cast: src[R][C] f32 -> dst[C][R] bf16 ----------------
__global__ void transpose_cast(const float* __restrict__ src, bf16* __restrict__ dst, int R, int C) {
    __shared__ float t[32][33];
    int c0 = blockIdx.x * 32, r0 = blockIdx.y * 32;
    int tx = threadIdx.x, ty = threadIdx.y; // block (32,8)
#pragma unroll
    for (int i = 0; i < 4; ++i)
        t[ty + i * 8][tx] = src[(long)(r0 + ty + i * 8) * C + c0 + tx];
    __syncthreads();
#pragma unroll
    for (int i = 0; i < 4; ++i)
        dst[(long)(c0 + ty + i * 8) * R + r0 + tx] = (bf16)t[tx][ty + i * 8];
}

// ---------------- concat 3 bias vectors (1024 each) ----------------
__global__ void concat3(const float* __restrict__ a, const float* __restrict__ b,
                        const float* __restrict__ c, float* __restrict__ out) {
    int i = blockIdx.x * 256 + threadIdx.x;
    if (i < 1024) out[i] = a[i];
    else if (i < 2048) out[i] = b[i - 1024];
    else if (i < 3072) out[i] = c[i - 2048];
}

// ---------------- build V^T: vt[(b*16+h)*64 + d][s] ----------------
__global__ void build_vt(const bf16* __restrict__ qkv, bf16* __restrict__ vt) {
    __shared__ bf16 t[32][33];
    int bh = blockIdx.z, b = bh >> 4, h = bh & 15;
    int s0 = blockIdx.x * 32, d0 = blockIdx.y * 32;
    int tx = threadIdx.x, ty = threadIdx.y;
#pragma unroll
    for (int i = 0; i < 4; ++i)
        t[ty + i * 8][tx] = qkv[(long)(b * SEQL + s0 + ty + i * 8) * 3072 + 2 * DM + h * DKH + d0 + tx];
    __syncthreads();
#pragma unroll
    for (int i = 0; i < 4; ++i)
        vt[((long)bh * DKH + d0 + ty + i * 8) * SEQL + s0 + tx] = (bf16)t[tx][ty + i * 8];
}

// ---------------- GEMM: 4-phase fine interleave + COUNTED vmcnt (r15 schedule) ----------------
// bf16 output only (split-K partials also bf16; summed in fp32 inside add_ln).
template<int BN>
__global__ __launch_bounds__(512, 2)
void gemm4ph(const bf16* __restrict__ A, const bf16* __restrict__ Bt,
             const float* __restrict__ bias,
             bf16* __restrict__ Ch,
             int N, int lda, int Klen, int relu, long strideCh) {
    constexpr int NR = BN / 64;            // 256->4, 192->3
    constexpr int WCOL = BN / 4;           // per-wave N extent
    __shared__ bf16 As[2][8][256][8];      // [buf][kg=k/8][row][8], BK=64
    __shared__ bf16 Bs[2][8][BN][8];
    const int tid = threadIdx.x;
    const int lane = tid & 63;
    const int wv = tid >> 6;
    const int wr = wv >> 2, wc = wv & 3;   // 2 x 4 wave grid
    const int lr = lane & 15, lg = lane >> 4;

    unsigned gx = gridDim.x, gy = gridDim.y;
    unsigned nwg = gx * gy * gridDim.z;
    unsigned wg = (blockIdx.z * gy + blockIdx.y) * gx + blockIdx.x;
    unsigned swz = (wg & 7) * (nwg >> 3) + (wg >> 3);
    unsigned bxi = swz % gx;
    unsigned rem2 = swz / gx;
    unsigned byi = rem2 % gy, bzi = rem2 / gy;

    const long brow = (long)byi * 256;
    const long bcol = (long)bxi * BN;
    const bf16* Ap = A + (long)bzi * Klen;
    const bf16* Bp = Bt + (long)bzi * Klen;
    bf16* Chp = Ch + (long)bzi * strideCh;
    const float* biasp = (bzi == 0) ? bias : nullptr;

    auto stageA = [&](int X, int h) {
        const int kt = X * 64, buf = X & 1;
#pragma unroll
        for (int j = 0; j < 2; ++j) {
            int l = j * 512 + tid;             // cell within half: 0..1023
            int kg = (l >> 8) + h * 4;
            int row = l & 255;
            gload_lds16(Ap + (brow + row) * (long)lda + kt + kg * 8, &As[buf][kg][row][0]);
        }
    };
    auto stageB = [&](int X, int h) {
        const int kt = X * 64, buf = X & 1;
        {
            int l = tid;                       // cells 0..511 of half
            int kg = l / BN + h * 4, row = l % BN;
            gload_lds16(Bp + (bcol + row) * (long)lda + kt + kg * 8, &Bs[buf][kg][row][0]);
        }
        {
            int l = 512 + (BN == 256 ? tid : (tid & 255));  // cells 512..(BN*4-1)
            int kg = l / BN + h * 4, row = l % BN;
            gload_lds16(Bp + (bcol + row) * (long)lda + kt + kg * 8, &Bs[buf][kg][row][0]);
        }
    };

    const int NT = Klen / 64;
    f32x4 acc[8][NR] = {};

    stageA(0, 0); stageB(0, 0); stageA(0, 1); stageB(0, 1);
    asm volatile("s_waitcnt vmcnt(4)" ::: "memory");
    __builtin_amdgcn_s_barrier();
    asm volatile("" ::: "memory");

    for (int T = 0; T < NT; ++T) {
        const int cur = T & 1;
        const bool pf = (T + 1 < NT);
        bf16x8 bv0[NR], bv1[NR], af[4];
        // ---------- ph0 ----------
#pragma unroll
        for (int n = 0; n < NR; ++n)
            bv0[n] = *(const bf16x8*)(&Bs[cur][lg][wc * WCOL + n * 16 + lr][0]);
#pragma unroll
        for (int m = 0; m < 4; ++m)
            af[m] = *(const bf16x8*)(&As[cur][lg][wr * 128 + m * 16 + lr][0]);
        if (pf) stageA(T + 1, 0);
        __builtin_amdgcn_s_barrier();
        asm volatile("s_waitcnt lgkmcnt(0)" ::: "memory");
        __builtin_amdgcn_sched_barrier(0);
        __builtin_amdgcn_s_setprio(1);
#pragma unroll
        for (int m = 0; m < 4; ++m)
#pragma unroll
            for (int n = 0; n < NR; ++n)
                acc[m][n] = __builtin_amdgcn_mfma_f32_16x16x32_bf16(af[m], bv0[n], acc[m][n], 0, 0, 0);
        __builtin_amdgcn_s_setprio(0);
        asm volatile("" ::: "memory");
        __builtin_amdgcn_s_barrier();
        // ---------- ph1 ----------
#pragma unroll
        for (int m = 0; m < 4; ++m)
            af[m] = *(const bf16x8*)(&As[cur][lg][wr * 128 + (4 + m) * 16 + lr][0]);
        if (pf) stageB(T + 1, 0);
        __builtin_amdgcn_s_barrier();
        asm volatile("s_waitcnt lgkmcnt(0)" ::: "memory");
        __builtin_amdgcn_sched_barrier(0);
        __builtin_amdgcn_s_setprio(1);
#pragma unroll
        for (int m = 0; m < 4; ++m)
#pragma unroll
            for (int n = 0; n < NR; ++n)
                acc[4 + m][n] = __builtin_amdgcn_mfma_f32_16x16x32_bf16(af[m], bv0[n], acc[4 + m][n], 0, 0, 0);
        __builtin_amdgcn_s_setprio(0);
        if (pf) asm volatile("s_waitcnt vmcnt(4)" ::: "memory");
        else    asm volatile("s_waitcnt vmcnt(0)" ::: "memory");
        asm volatile("" ::: "memory");
        __builtin_amdgcn_s_barrier();
        // ---------- ph2 ----------
#pragma unroll
        for (int n = 0; n < NR; ++n)
            bv1[n] = *(const bf16x8*)(&Bs[cur][4 + lg][wc * WCOL + n * 16 + lr][0]);
#pragma unroll
        for (int m = 0; m < 4; ++m)
            af[m] = *(const bf16x8*)(&As[cur][4 + lg][wr * 128 + m * 16 + lr][0]);
        if (pf) stageA(T + 1, 1);
        __builtin_amdgcn_s_barrier();
        asm volatile("s_waitcnt lgkmcnt(0)" ::: "memory");
        __builtin_amdgcn_sched_barrier(0);
        __builtin_amdgcn_s_setprio(1);
#pragma unroll
        for (int m = 0; m < 4; ++m)
#pragma unroll
            for (int n = 0; n < NR; ++n)
                acc[m][n] = __builtin_amdgcn_mfma_f32_16x16x32_bf16(af[m], bv1[n], acc[m][n], 0, 0, 0);
        __builtin_amdgcn_s_setprio(0);
        asm volatile("" ::: "memory");
        __builtin_amdgcn_s_barrier();
        // ---------- ph3 ----------
#pragma unroll
        for (int m = 0; m < 4; ++m)
            af[m] = *(const bf16x8*)(&As[cur][4 + lg][wr * 128 + (4 + m) * 16 + lr][0]);
        if (pf) stageB(T + 1, 1);
        __builtin_amdgcn_s_barrier();
        asm volatile("s_waitcnt lgkmcnt(0)" ::: "memory");
        __builtin_amdgcn_sched_barrier(0);
        __builtin_amdgcn_s_setprio(1);
#pragma unroll
        for (int m = 0; m < 4; ++m)
#pragma unroll
            for (int n = 0; n < NR; ++n)
                acc[4 + m][n] = __builtin_amdgcn_mfma_f32_16x16x32_bf16(af[m], bv1[n], acc[4 + m][n], 0, 0, 0);
        __builtin_amdgcn_s_setprio(0);
        if (pf) asm volatile("s_waitcnt vmcnt(4)" ::: "memory");
        asm volatile("" ::: "memory");
        __builtin_amdgcn_s_barrier();
    }

#pragma unroll
    for (int m = 0; m < 8; ++m) {
#pragma unroll
        for (int n = 0; n < NR; ++n) {
            long gcol = bcol + wc * WCOL + n * 16 + lr;
            float bv = biasp ? biasp[gcol] : 0.f;
#pragma unroll
            for (int r = 0; r < 4; ++r) {
                long grow = brow + wr * 128 + m * 16 + lg * 4 + r;
                float v = acc[m][n][r] + bv;
                if (relu) v = v > 0.f ? v : 0.f;
                Chp[grow * N + gcol] = (bf16)v;
            }
        }
    }
}

// ---------------- flash attention (r16 best, verbatim) ----------------
__global__ __launch_bounds__(256, 3)
void attn_fwd(const bf16* __restrict__ qkv, const bf16* __restrict__ vt,
              bf16* __restrict__ attn_o) {
    __shared__ bf16 Ks[2][64][64];   // [buf][kv][d], swizzled
    __shared__ bf16 Vs[2][64][64];   // [buf][d][kv], swizzled
    __shared__ bf16 Plds[4][16][64]; // per-wave P tile [q][kv], swizzled
    const int tid = threadIdx.x, lane = tid & 63, w = tid >> 6;
    const int lr = lane & 15, lg = lane >> 4;

    unsigned nwg = gridDim.x * gridDim.y;       // 1024
    unsigned wg = blockIdx.y * gridDim.x + blockIdx.x;
    unsigned cpx = nwg >> 3;
    unsigned swzid = (wg & 7) * cpx + (wg >> 3);
    const int bx = swzid % gridDim.x, bh = swzid / gridDim.x;
    const int b = bh >> 4, h = bh & 15;
    const int q0 = bx * 128 + w * 32;

    const bf16* Q  = qkv + (long)b * SEQL * 3072 + h * DKH;
    const bf16* Kp = qkv + (long)b * SEQL * 3072 + DM + h * DKH;
    const bf16* Vp = vt + (long)bh * DKH * SEQL;

    const int r0 = w * 8 + (lane >> 3);
    const int cbb = ((lane & 7) * 16) ^ ((r0 & 7) << 4);
    const int cb = cbb >> 1;

    auto stage = [&](int buf, int j0) {
#pragma unroll
        for (int c = 0; c < 2; ++c) {
            bf16* kd = &Ks[buf][0][0] + c * 2048 + w * 512 + lane * 8;
            bf16* vd = &Vs[buf][0][0] + c * 2048 + w * 512 + lane * 8;
            gload_lds16(Kp + (long)(j0 + c * 32 + r0) * 3072 + cb, kd);
            gload_lds16(Vp + (long)(c * 32 + r0) * SEQL + j0 + cb, vd);
        }
    };

    stage(0, 0);

    // Q pre-scale: (1/sqrt(64)) * log2(e) -> scores land in log2 domain
    const float QSC = 0.125f * 1.44269504f;
    bf16x8 aq[2][2];
#pragma unroll
    for (int a = 0; a < 2; ++a)
#pragma unroll
        for (int kh = 0; kh < 2; ++kh) {
            bf16x8 q = *(const bf16x8*)(Q + (long)(q0 + a * 16 + lr) * 3072 + kh * 32 + lg * 8);
#pragma unroll
            for (int e = 0; e < 8; ++e) q[e] = (bf16)((float)q[e] * QSC);
            aq[a][kh] = q;
        }

    float mrow[2] = {-1e30f, -1e30f};
    float lrow[2] = {0.f, 0.f};   // LANE-PARTIAL sums
    f32x4 accO[2][4] = {};
    char* pbase = (char*)&Plds[w][0][0];
    const int psw = (lr & 7) << 4;
    const f32x4 zero = {0.f, 0.f, 0.f, 0.f};
    int cur = 0;

    for (int it = 0; it < SEQL / 64; ++it) {
        if (it < SEQL / 64 - 1) {
            stage(cur ^ 1, (it + 1) * 64);
            asm volatile("s_waitcnt vmcnt(4)" ::: "memory");
        } else {
            asm volatile("s_waitcnt vmcnt(0)" ::: "memory");
        }
        __builtin_amdgcn_s_barrier();
        asm volatile("" ::: "memory");

        const char* Kbuf = (const char*)&Ks[cur][0][0];
        const char* Vbuf = (const char*)&Vs[cur][0][0];

        bf16x8 kf[4][2];
#pragma unroll
        for (int jh = 0; jh < 4; ++jh) {
            int row = jh * 16 + lr;
            int sw = (row & 7) << 4;
            kf[jh][0] = *(const bf16x8*)(Kbuf + row * 128 + ((lg * 16) ^ sw));
            kf[jh][1] = *(const bf16x8*)(Kbuf + row * 128 + ((64 + lg * 16) ^ sw));
        }
        bf16x8 vf[4][2];
#pragma unroll
        for (int c = 0; c < 4; ++c) {
            int row = c * 16 + lr;
            int sw = (row & 7) << 4;
            vf[c][0] = *(const bf16x8*)(Vbuf + row * 128 + ((lg * 16) ^ sw));
            vf[c][1] = *(const bf16x8*)(Vbuf + row * 128 + ((64 + lg * 16) ^ sw));
        }

#pragma unroll
        for (int a = 0; a < 2; ++a) {
            f32x4 s[4];
#pragma unroll
            for (int jh = 0; jh < 4; ++jh) {
                f32x4 t = __builtin_amdgcn_mfma_f32_16x16x32_bf16(kf[jh][0], aq[a][0], zero, 0, 0, 0);
                s[jh] = __builtin_amdgcn_mfma_f32_16x16x32_bf16(kf[jh][1], aq[a][1], t, 0, 0, 0);
            }
            float m0 = fmaxf(fmaxf(s[0][0], s[0][1]), fmaxf(s[0][2], s[0][3]));
            float m1 = fmaxf(fmaxf(s[1][0], s[1][1]), fmaxf(s[1][2], s[1][3]));
            float m2 = fmaxf(fmaxf(s[2][0], s[2][1]), fmaxf(s[2][2], s[2][3]));
            float m3 = fmaxf(fmaxf(s[3][0], s[3][1]), fmaxf(s[3][2], s[3][3]));
            float pmloc = fmaxf(fmaxf(m0, m1), fmaxf(m2, m3));
            int skip = __all(pmloc - mrow[a] <= 8.0f);
            if (!skip) {
                float pm = fmaxf(pmloc, __shfl_xor(pmloc, 16));
                pm = fmaxf(pm, __shfl_xor(pm, 32));
                float mnew = fmaxf(mrow[a], pm);
                float al = fast_exp2(mrow[a] - mnew);
                mrow[a] = mnew;
                lrow[a] *= al;
                float alr[4];
#pragma unroll
                for (int r = 0; r < 4; ++r)
                    alr[r] = __shfl(al, (lane & 48) | (lg * 4 + r));
#pragma unroll
                for (int c = 0; c < 4; ++c)
#pragma unroll
                    for (int r = 0; r < 4; ++r) accO[a][c][r] *= alr[r];
            }
            float mcur = mrow[a];
            float psum = 0.f;
#pragma unroll
            for (int jh = 0; jh < 4; ++jh)
#pragma unroll
                for (int r = 0; r < 4; ++r) {
                    float p = fast_exp2(s[jh][r] - mcur);
                    s[jh][r] = p;
                    psum += p;
                }
            lrow[a] += psum;
#pragma unroll
            for (int jh = 0; jh < 4; ++jh) {
                bf16x4 pw = {(bf16)s[jh][0], (bf16)s[jh][1], (bf16)s[jh][2], (bf16)s[jh][3]};
                *(bf16x4*)(pbase + lr * 128 + ((jh * 32 + lg * 8) ^ psw)) = pw;
            }
            bf16x8 pa[2];
#pragma unroll
            for (int i = 0; i < 2; ++i)
                pa[i] = *(const bf16x8*)(pbase + lr * 128 + ((i * 64 + lg * 16) ^ psw));
#pragma unroll
            for (int c = 0; c < 4; ++c) {
                accO[a][c] = __builtin_amdgcn_mfma_f32_16x16x32_bf16(pa[0], vf[c][0], accO[a][c], 0, 0, 0);
                accO[a][c] = __builtin_amdgcn_mfma_f32_16x16x32_bf16(pa[1], vf[c][1], accO[a][c], 0, 0, 0);
            }
        }
        asm volatile("" ::: "memory");
        __builtin_amdgcn_s_barrier();
        cur ^= 1;
    }

#pragma unroll
    for (int a = 0; a < 2; ++a) {
        float lsum = lrow[a];
        lsum += __shfl_xor(lsum, 16);
        lsum += __shfl_xor(lsum, 32);
        float linv = 1.0f / lsum;
        float invr[4];
#pragma unroll
        for (int r = 0; r < 4; ++r)
            invr[r] = __shfl(linv, (lane & 48) | (lg * 4 + r));
#pragma unroll
        for (int r = 0; r < 4; ++r) {
            long grow = (long)b * SEQL + q0 + a * 16 + lg * 4 + r;
#pragma unroll
            for (int c = 0; c < 4; ++c)
                attn_o[grow * DM + h * DKH + c * 16 + lr] = (bf16)(accO[a][c][r] * invr[r]);
        }
    }
}

// ---------------- fused residual add (bf16 partials) + LayerNorm ----------------
// AISF32: residual dtype (1 = fp32 [x], 0 = bf16 [x1h]). B,B2 = bf16 split-K
// partials summed in fp32. Outputs: fp32 (final) and/or bf16.
template<int AISF32>
__global__ __launch_bounds__(256)
void add_ln(const void* __restrict__ Ap, const bf16* __restrict__ B,
            const bf16* __restrict__ B2,
            const float* __restrict__ g, const float* __restrict__ be,
            float* __restrict__ outf, bf16* __restrict__ outh) {
    const int w = threadIdx.x >> 6, lane = threadIdx.x & 63;
    const long row = (long)blockIdx.x * 4 + w;
    float4 v[4];
    float s = 0.f;
#pragma unroll
    for (int i = 0; i < 4; ++i) {
        int sl = i * 64 + lane;
        float4 a;
        if (AISF32) {
            a = ((const float4*)((const float*)Ap + row * DM))[sl];
        } else {
            bf16x4 ah = ((const bf16x4*)((const bf16*)Ap + row * DM))[sl];
            a = make_float4((float)ah[0], (float)ah[1], (float)ah[2], (float)ah[3]);
        }
        bf16x4 bh = ((const bf16x4*)(B + row * DM))[sl];
        bf16x4 b2h = ((const bf16x4*)(B2 + row * DM))[sl];
        v[i] = make_float4(a.x + (float)bh[0] + (float)b2h[0],
                           a.y + (float)bh[1] + (float)b2h[1],
                           a.z + (float)bh[2] + (float)b2h[2],
                           a.w + (float)bh[3] + (float)b2h[3]);
        s += v[i].x + v[i].y + v[i].z + v[i].w;
    }
#pragma unroll
    for (int off = 32; off; off >>= 1) s += __shfl_xor(s, off);
    float mu = s * (1.0f / 1024.0f);
    float var = 0.f;
#pragma unroll
    for (int i = 0; i < 4; ++i) {
        float dx = v[i].x - mu, dy = v[i].y - mu, dz = v[i].z - mu, dw = v[i].w - mu;
        var += dx * dx + dy * dy + dz * dz + dw * dw;
    }
#pragma unroll
    for (int off = 32; off; off >>= 1) var += __shfl_xor(var, off);
    float rs = 1.0f / sqrtf(var * (1.0f / 1024.0f) + 1e-5f);
    const float4* pg = (const float4*)g;
    const float4* pe = (const float4*)be;
#pragma unroll
    for (int i = 0; i < 4; ++i) {
        float4 gg = pg[i * 64 + lane], ee = pe[i * 64 + lane];
        float4 o = make_float4((v[i].x - mu) * rs * gg.x + ee.x,
                               (v[i].y - mu) * rs * gg.y + ee.y,
                               (v[i].z - mu) * rs * gg.z + ee.z,
                               (v[i].w - mu) * rs * gg.w + ee.w);
        if (outf) ((float4*)(outf + row * DM))[i * 64 + lane] = o;
        if (outh) {
            bf16x4 ho = {(bf16)o.x, (bf16)o.y, (bf16)o.z, (bf16)o.w};
            *(bf16x4*)(outh + row * DM + (i * 64 + lane) * 4) = ho;
        }
    }
}

extern "C" void kernel_launch(void* const* d_in, const int* in_sizes, int n_in,
                              void* d_out, int out_size, void* d_ws, size_t ws_size,
                              hipStream_t stream) {
    const float* x   = (const float*)d_in[0];
    const float* Wq  = (const float*)d_in[1];
    const float* bq  = (const float*)d_in[2];
    const float* Wk  = (const float*)d_in[3];
    const float* bk  = (const float*)d_in[4];
    const float* Wv  = (const float*)d_in[5];
    const float* bv  = (const float*)d_in[6];
    const float* Wo  = (const float*)d_in[7];
    const float* bo  = (const float*)d_in[8];
    const float* W1  = (const float*)d_in[9];
    const float* b1  = (const float*)d_in[10];
    const float* W2  = (const float*)d_in[11];
    const float* b2  = (const float*)d_in[12];
    const float* g1  = (const float*)d_in[13];
    const float* be1 = (const float*)d_in[14];
    const float* g2  = (const float*)d_in[15];
    const float* be2 = (const float*)d_in[16];
    float* out = (float*)d_out;

    char* ws = (char*)d_ws;
    size_t off = 0;
    auto alloc = [&](size_t bytes) {
        void* p = ws + off;
        off += (bytes + 255) & ~(size_t)255;
        return p;
    };
    bf16* xh    = (bf16*)alloc((size_t)NTOK * DM * 2);
    bf16* wqkvt = (bf16*)alloc((size_t)3072 * 1024 * 2);
    bf16* wot   = (bf16*)alloc((size_t)1024 * 1024 * 2);
    bf16* w1t   = (bf16*)alloc((size_t)4096 * 1024 * 2);
    bf16* w2t   = (bf16*)alloc((size_t)1024 * 4096 * 2);
    float* bqkv = (float*)alloc((size_t)3072 * 4);
    bf16* qkv   = (bf16*)alloc((size_t)NTOK * 3072 * 2);
    bf16* vtb   = (bf16*)alloc((size_t)NTOK * DM * 2);
    bf16* attno = (bf16*)alloc((size_t)NTOK * DM * 2);
    bf16* proj0 = (bf16*)alloc((size_t)NTOK * DM * 2);   // split-K partial 0 (bf16)
    bf16* proj1 = (bf16*)alloc((size_t)NTOK * DM * 2);   // split-K partial 1 (bf16)
    bf16* x1h   = (bf16*)alloc((size_t)NTOK * DM * 2);   // LN1 out = FFN1 in = LN2 residual
    bf16* ffh   = (bf16*)qkv; // alias: qkv+vtb dead after attn; 67MB for [8192][4096]

    dim3 tb(32, 8);
    cast_f32_bf16<<<2048, 256, 0, stream>>>(x, xh, (long)NTOK * DM);
    transpose_cast<<<dim3(32, 32), tb, 0, stream>>>(Wq, wqkvt, 1024, 1024);
    transpose_cast<<<dim3(32, 32), tb, 0, stream>>>(Wk, wqkvt + (size_t)1024 * 1024, 1024, 1024);
    transpose_cast<<<dim3(32, 32), tb, 0, stream>>>(Wv, wqkvt + (size_t)2048 * 1024, 1024, 1024);
    transpose_cast<<<dim3(32, 32), tb, 0, stream>>>(Wo, wot, 1024, 1024);
    transpose_cast<<<dim3(128, 32), tb, 0, stream>>>(W1, w1t, 1024, 4096);
    transpose_cast<<<dim3(32, 128), tb, 0, stream>>>(W2, w2t, 4096, 1024);
    concat3<<<12, 256, 0, stream>>>(bq, bk, bv, bqkv);

    // QKV: [8192,1024]@[1024,3072] -> bf16 (BN=192: grid 16x32=512 = 2 even rounds)
    gemm4ph<192><<<dim3(3072 / 192, 8192 / 256, 1), 512, 0, stream>>>(
        xh, wqkvt, bqkv, qkv, 3072, 1024, 1024, 0, 0);
    build_vt<<<dim3(SEQL / 32, 2, 64), tb, 0, stream>>>(qkv, vtb);
    attn_fwd<<<dim3(SEQL / 128, 64), 256, 0, stream>>>(qkv, vtb, attno);
    // Wo: split-K x2 (Klen=512), grid 4x32x2=256 -> bf16 partials proj0/proj1
    gemm4ph<256><<<dim3(1024 / 256, 8192 / 256, 2), 512, 0, stream>>>(
        attno, wot, bo, proj0, 1024, 1024, 512, 0, (long)NTOK * DM);
    add_ln<1><<<NTOK / 4, 256, 0, stream>>>(x, proj0, proj1, g1, be1, nullptr, x1h);
    // FFN1: [8192,1024]@[1024,4096]+ReLU -> bf16 (grid 16x32=512)
    gemm4ph<256><<<dim3(4096 / 256, 8192 / 256, 1), 512, 0, stream>>>(
        x1h, w1t, b1, ffh, 4096, 1024, 1024, 1, 0);
    // FFN2: split-K x2 (Klen=2048), grid 4x32x2=256 -> bf16 partials proj0/proj1
    gemm4ph<256><<<dim3(1024 / 256, 8192 / 256, 2), 512, 0, stream>>>(
        ffh, w2t, b2, proj0, 1024, 4096, 2048, 0, (long)NTOK * DM);
    add_ln<0><<<NTOK / 4, 256, 0, stream>>>(x1h, proj0, proj1, g2, be2, out, nullptr);
}